// Round 7
// baseline (505.429 us; speedup 1.0000x reference)
//
#include <hip/hip_runtime.h>
#include <hip/hip_bf16.h>
#include <hip/hip_fp16.h>

#define Nn 50000
#define Ee 1000000
#define Bb 512
#define NG 3125   // 50000/16 node-row groups (exact)
#define SCB 196   // ceil(50000/256) scan blocks

typedef unsigned short u16;
typedef unsigned int u32;
typedef _Float16 f16;
typedef _Float16 f16x8 __attribute__((ext_vector_type(8)));
typedef float f32x4 __attribute__((ext_vector_type(4)));

__device__ __forceinline__ u16 f2h(float f) { return __half_as_ushort(__float2half(f)); }
__device__ __forceinline__ float h2f_lo(u32 kv) { return __half2float(__ushort_as_half((u16)(kv & 0xffff))); }
__device__ __forceinline__ float h2f_hi(u32 kv) { return __half2float(__ushort_as_half((u16)(kv >> 16))); }

// 2^x in one VALU op
__device__ __forceinline__ float fexp2(float x) {
    float r;
    asm("v_exp_f32 %0, %1" : "=v"(r) : "v"(x));
    return r;
}

// butterfly sum over each 16-lane group (one head) via DPP
__device__ __forceinline__ float red16(float x) {
    int t;
    t = __builtin_amdgcn_update_dpp(0, __float_as_int(x), 0xB1, 0xF, 0xF, true);   // quad_perm [1,0,3,2]
    x += __int_as_float(t);
    t = __builtin_amdgcn_update_dpp(0, __float_as_int(x), 0x4E, 0xF, 0xF, true);   // quad_perm [2,3,0,1]
    x += __int_as_float(t);
    t = __builtin_amdgcn_update_dpp(0, __float_as_int(x), 0x141, 0xF, 0xF, true);  // row_half_mirror (xor7)
    x += __int_as_float(t);
    t = __builtin_amdgcn_update_dpp(0, __float_as_int(x), 0x140, 0xF, 0xF, true);  // row_mirror (xor15)
    x += __int_as_float(t);
    return x;
}

// ---------------- input projection: X = x @ W_in + b_in ----------------
__global__ __launch_bounds__(256) void k_input_proj(const float* __restrict__ x,
    const float* __restrict__ Win, const float* __restrict__ bin, float* __restrict__ X)
{
    __shared__ float W[8][64];
    __shared__ float bsh[64];
    int t = threadIdx.x;
    if (t < 64) bsh[t] = bin[t];
    for (int i = t; i < 512; i += 256) W[i >> 6][i & 63] = Win[i];
    __syncthreads();
    int gid = blockIdx.x * 256 + t;
    int n = gid >> 6, c = gid & 63;
    const float* xr = x + n * 8;
    float acc = bsh[c];
#pragma unroll
    for (int k = 0; k < 8; ++k) acc = fmaf(xr[k], W[k][c], acc);
    X[gid] = acc;
}

// ---------------- CSR build ----------------
__global__ __launch_bounds__(256) void k_hist(const int* __restrict__ ei, int* __restrict__ deg)
{
    int e = blockIdx.x * 256 + threadIdx.x;
    if (e < Ee) atomicAdd(&deg[ei[Ee + e]], 1);
}

__global__ __launch_bounds__(256) void k_part(const int* __restrict__ deg, int* __restrict__ psum)
{
    __shared__ int ws[4];
    int b = blockIdx.x, t = threadIdx.x;
    int idx = b * 256 + t;
    int v = (idx < Nn) ? deg[idx] : 0;
    int r = v;
#pragma unroll
    for (int off = 32; off; off >>= 1) r += __shfl_xor(r, off);
    if ((t & 63) == 0) ws[t >> 6] = r;
    __syncthreads();
    if (t == 0) psum[b] = ws[0] + ws[1] + ws[2] + ws[3];
}

__global__ __launch_bounds__(256) void k_scanp(const int* __restrict__ psum, int* __restrict__ poff)
{
    __shared__ int ws[4];
    int t = threadIdx.x, lane = t & 63, w = t >> 6;
    int v = (t < SCB) ? psum[t] : 0;
    int s = v;
#pragma unroll
    for (int off = 1; off < 64; off <<= 1) {
        int u = __shfl_up(s, off);
        if (lane >= off) s += u;
    }
    if (lane == 63) ws[w] = s;
    __syncthreads();
    if (t == 0) { int a = 0; for (int i = 0; i < 4; ++i) { a += ws[i]; ws[i] = a; } }
    __syncthreads();
    int incl = s + (w ? ws[w - 1] : 0);
    if (t < SCB) poff[t] = incl - v;
}

__global__ __launch_bounds__(256) void k_apply(const int* __restrict__ deg, const int* __restrict__ poff,
    int* __restrict__ rowptr)
{
    __shared__ int ws[4];
    int b = blockIdx.x, t = threadIdx.x, lane = t & 63, w = t >> 6;
    int idx = b * 256 + t;
    int v = (idx < Nn) ? deg[idx] : 0;
    int s = v;
#pragma unroll
    for (int off = 1; off < 64; off <<= 1) {
        int u = __shfl_up(s, off);
        if (lane >= off) s += u;
    }
    if (lane == 63) ws[w] = s;
    __syncthreads();
    if (t == 0) { int a = 0; for (int i = 0; i < 4; ++i) { a += ws[i]; ws[i] = a; } }
    __syncthreads();
    int incl = s + (w ? ws[w - 1] : 0) + poff[b];
    if (idx < Nn) rowptr[idx + 1] = incl;
    if (b == 0 && t == 0) rowptr[0] = 0;
}

// phase A: scatter only the 4-byte permutation
__global__ __launch_bounds__(256) void k_perm(const int* __restrict__ ei,
    const int* __restrict__ rowptr, int* __restrict__ cursor, int* __restrict__ perm)
{
    int e = blockIdx.x * 256 + threadIdx.x;
    if (e >= Ee) return;
    int d = ei[Ee + e];
    int pos = rowptr[d] + atomicAdd(&cursor[d], 1);
    perm[pos] = e;
}

// phase B: gather edge data via perm, write colsrc + ea4 fully coalesced
__global__ __launch_bounds__(256) void k_pack(const int* __restrict__ ei,
    const float* __restrict__ eattr, const int* __restrict__ perm,
    int* __restrict__ colsrc, float4* __restrict__ ea4)
{
    int p = blockIdx.x * 256 + threadIdx.x;
    if (p >= Ee) return;
    int e = perm[p];
    colsrc[p] = ei[e];
    ea4[p] = *(const float4*)(eattr + (size_t)e * 4);
}

// ---------------- MFMA helpers ----------------
__device__ __forceinline__ f16x8 load_bfrag(const float* __restrict__ W, int NC, int col, int k0)
{
    f16x8 b;
    const float* wp = W + (size_t)k0 * NC + col;
#pragma unroll
    for (int i = 0; i < 8; ++i) b[i] = (f16)wp[i * NC];
    return b;
}

__device__ __forceinline__ void build_ln_a(const float* __restrict__ X, int n0, int lane,
    const float* __restrict__ lng, const float* __restrict__ lnb, f16x8* a)
{
    const int r = lane & 15, c = lane >> 4;
    const float* xp = X + (size_t)(n0 + r) * 64 + c * 8;
    float4 x0 = *(const float4*)(xp);
    float4 x1 = *(const float4*)(xp + 4);
    float4 x2 = *(const float4*)(xp + 32);
    float4 x3 = *(const float4*)(xp + 36);
    float xs[16] = {x0.x, x0.y, x0.z, x0.w, x1.x, x1.y, x1.z, x1.w,
                    x2.x, x2.y, x2.z, x2.w, x3.x, x3.y, x3.z, x3.w};
    float s = 0.f, s2 = 0.f;
#pragma unroll
    for (int i = 0; i < 16; ++i) { s += xs[i]; s2 = fmaf(xs[i], xs[i], s2); }
    s += __shfl_xor(s, 16);  s += __shfl_xor(s, 32);
    s2 += __shfl_xor(s2, 16); s2 += __shfl_xor(s2, 32);
    float mu = s * 0.015625f;
    float var = s2 * 0.015625f - mu * mu;
    float rstd = rsqrtf(fmaxf(var, 0.f) + 1e-5f);
    const float* gp = lng + c * 8;
    const float* bp = lnb + c * 8;
    float4 g0 = *(const float4*)(gp),      g1 = *(const float4*)(gp + 4);
    float4 g2 = *(const float4*)(gp + 32), g3 = *(const float4*)(gp + 36);
    float4 b0 = *(const float4*)(bp),      b1 = *(const float4*)(bp + 4);
    float4 b2 = *(const float4*)(bp + 32), b3 = *(const float4*)(bp + 36);
    float gs[16] = {g0.x, g0.y, g0.z, g0.w, g1.x, g1.y, g1.z, g1.w,
                    g2.x, g2.y, g2.z, g2.w, g3.x, g3.y, g3.z, g3.w};
    float bs[16] = {b0.x, b0.y, b0.z, b0.w, b1.x, b1.y, b1.z, b1.w,
                    b2.x, b2.y, b2.z, b2.w, b3.x, b3.y, b3.z, b3.w};
#pragma unroll
    for (int i = 0; i < 16; ++i) {
        float h = (xs[i] - mu) * rstd * gs[i] + bs[i];
        a[i >> 3][i & 7] = (f16)h;
    }
}

// ---------------- LN1 + K,V projection -> packed f16 KV ----------------
__global__ __launch_bounds__(256) void k_proj_kv(const float* __restrict__ X, u32* __restrict__ KV,
    const float* __restrict__ Wk, const float* __restrict__ Wv,
    const float* __restrict__ bk, const float* __restrict__ bv,
    const float* __restrict__ lng, const float* __restrict__ lnb)
{
    const int lane = threadIdx.x & 63;
    const int wid = (blockIdx.x * 256 + threadIdx.x) >> 6;
    const int nw = gridDim.x * 4;
    const int ch_base = lane & 15;
    const int k0b = (lane >> 4) * 8;
    f16x8 bw[8][2];
#pragma unroll
    for (int t = 0; t < 4; ++t)
#pragma unroll
        for (int s = 0; s < 2; ++s) {
            bw[t][s]     = load_bfrag(Wk, 64, t * 16 + ch_base, s * 32 + k0b);
            bw[t + 4][s] = load_bfrag(Wv, 64, t * 16 + ch_base, s * 32 + k0b);
        }
    float bk_l[4], bv_l[4];
#pragma unroll
    for (int t = 0; t < 4; ++t) { bk_l[t] = bk[t * 16 + ch_base]; bv_l[t] = bv[t * 16 + ch_base]; }
    for (int g = wid; g < NG; g += nw) {
        int n0 = g * 16;
        f16x8 a[2];
        build_ln_a(X, n0, lane, lng, lnb, a);
        f32x4 acc[8];
#pragma unroll
        for (int t = 0; t < 8; ++t) { acc[t][0] = 0.f; acc[t][1] = 0.f; acc[t][2] = 0.f; acc[t][3] = 0.f; }
#pragma unroll
        for (int t = 0; t < 8; ++t)
#pragma unroll
            for (int s = 0; s < 2; ++s)
                acc[t] = __builtin_amdgcn_mfma_f32_16x16x32_f16(a[s], bw[t][s], acc[t], 0, 0, 0);
        int rbase = n0 + (lane >> 4) * 4;
#pragma unroll
        for (int t = 0; t < 4; ++t) {
            int ch = t * 16 + ch_base;
#pragma unroll
            for (int j = 0; j < 4; ++j) {
                u32 lo = f2h(acc[t][j] + bk_l[t]);
                u32 hi = f2h(acc[t + 4][j] + bv_l[t]);
                KV[(size_t)(rbase + j) * 64 + ch] = (hi << 16) | lo;
            }
        }
    }
}

// ---------------- LN1 + Q,Skip projection -> QX f32 [q(64)|xr(64)] ----------------
__global__ __launch_bounds__(256) void k_proj_qs(const float* __restrict__ X, float* __restrict__ QX,
    const float* __restrict__ Wq, const float* __restrict__ Ws,
    const float* __restrict__ bq, const float* __restrict__ bs_,
    const float* __restrict__ lng, const float* __restrict__ lnb)
{
    const int lane = threadIdx.x & 63;
    const int wid = (blockIdx.x * 256 + threadIdx.x) >> 6;
    const int nw = gridDim.x * 4;
    const int ch_base = lane & 15;
    const int k0b = (lane >> 4) * 8;
    f16x8 bw[8][2];
#pragma unroll
    for (int t = 0; t < 4; ++t)
#pragma unroll
        for (int s = 0; s < 2; ++s) {
            bw[t][s]     = load_bfrag(Wq, 64, t * 16 + ch_base, s * 32 + k0b);
            bw[t + 4][s] = load_bfrag(Ws, 64, t * 16 + ch_base, s * 32 + k0b);
        }
    float bq_l[4], bs_l[4];
#pragma unroll
    for (int t = 0; t < 4; ++t) { bq_l[t] = bq[t * 16 + ch_base]; bs_l[t] = bs_[t * 16 + ch_base]; }
    for (int g = wid; g < NG; g += nw) {
        int n0 = g * 16;
        f16x8 a[2];
        build_ln_a(X, n0, lane, lng, lnb, a);
        f32x4 acc[8];
#pragma unroll
        for (int t = 0; t < 8; ++t) { acc[t][0] = 0.f; acc[t][1] = 0.f; acc[t][2] = 0.f; acc[t][3] = 0.f; }
#pragma unroll
        for (int t = 0; t < 8; ++t)
#pragma unroll
            for (int s = 0; s < 2; ++s)
                acc[t] = __builtin_amdgcn_mfma_f32_16x16x32_f16(a[s], bw[t][s], acc[t], 0, 0, 0);
        int rbase = n0 + (lane >> 4) * 4;
#pragma unroll
        for (int t = 0; t < 4; ++t) {
            int ch = t * 16 + ch_base;
#pragma unroll
            for (int j = 0; j < 4; ++j) {
                float* dst = QX + (size_t)(rbase + j) * 128;
                dst[ch] = acc[t][j] + bq_l[t];
                dst[64 + ch] = acc[t + 4][j] + bs_l[t];
            }
        }
    }
}

// ---------------- edge attention: one wave/node, no-max online softmax, DPP reduce ----------------
__global__ __launch_bounds__(256) void k_edge(
    const float* __restrict__ QX, const u32* __restrict__ KV, float* __restrict__ X,
    const int* __restrict__ rowptr, const int* __restrict__ colsrc,
    const float4* __restrict__ ea4,
    const float* __restrict__ We, const float* __restrict__ Wbeta)
{
    const float SCL = 0.25f * 1.4426950408889634f;  // 1/sqrt(D) * log2(e)
    int lane = threadIdx.x & 63;
    int node = blockIdx.x * 4 + (threadIdx.x >> 6);
    if (node >= Nn) return;
    float we0 = We[lane], we1 = We[64 + lane];
    float we2 = We[128 + lane], we3 = We[192 + lane];
    float wbA = Wbeta[lane] + Wbeta[128 + lane];
    float wbB = Wbeta[64 + lane] - Wbeta[128 + lane];
    const float* qrow = QX + (size_t)node * 128;
    float q = qrow[lane] * SCL;
    float xr = qrow[64 + lane];
    int jb = rowptr[node], je = rowptr[node + 1];
    float l0 = 0.f, l1 = 0.f, a0 = 0.f, a1 = 0.f;
    int j = jb;
    for (; j + 3 < je; j += 4) {
        int src[4]; float4 eb[4]; u32 kv[4];
#pragma unroll
        for (int c = 0; c < 4; ++c) src[c] = colsrc[j + c];
#pragma unroll
        for (int c = 0; c < 4; ++c) kv[c] = KV[(src[c] << 6) | lane];
#pragma unroll
        for (int c = 0; c < 4; ++c) eb[c] = ea4[j + c];
        float pe[4], ve[4];
#pragma unroll
        for (int c = 0; c < 4; ++c) {
            float e = we0 * eb[c].x;
            e = fmaf(we1, eb[c].y, e); e = fmaf(we2, eb[c].z, e); e = fmaf(we3, eb[c].w, e);
            float ke = h2f_lo(kv[c]) + e;
            ve[c] = h2f_hi(kv[c]) + e;
            float p = red16(q * ke);
            pe[c] = fexp2(p);
        }
        l0 += pe[0]; l1 += pe[1];
        a0 = fmaf(pe[0], ve[0], a0); a1 = fmaf(pe[1], ve[1], a1);
        l0 += pe[2]; l1 += pe[3];
        a0 = fmaf(pe[2], ve[2], a0); a1 = fmaf(pe[3], ve[3], a1);
    }
    for (; j < je; ++j) {
        int s0 = colsrc[j];
        float4 eb0 = ea4[j];
        u32 kv0 = KV[(s0 << 6) | lane];
        float e0 = we0 * eb0.x;
        e0 = fmaf(we1, eb0.y, e0); e0 = fmaf(we2, eb0.z, e0); e0 = fmaf(we3, eb0.w, e0);
        float ke0 = h2f_lo(kv0) + e0, ve0 = h2f_hi(kv0) + e0;
        float p0 = red16(q * ke0);
        float pe0 = fexp2(p0);
        l0 += pe0;
        a0 = fmaf(pe0, ve0, a0);
    }
    float lsum = l0 + l1;
    float acc = a0 + a1;
    float outv = acc / (lsum + 1e-16f);
    float tb = outv * wbA + xr * wbB;
#pragma unroll
    for (int off = 32; off; off >>= 1) tb += __shfl_xor(tb, off);
    float beta = 1.f / (1.f + __expf(-tb));
    float res = beta * xr + (1.f - beta) * outv;
    X[(size_t)node * 64 + lane] += res;
}

// ---------------- LN2 + FFN1 (64->128) + GELU -> G f16 ----------------
__global__ __launch_bounds__(256) void k_ffn1_m(const float* __restrict__ X, u16* __restrict__ G16,
    const float* __restrict__ W1, const float* __restrict__ b1,
    const float* __restrict__ lng, const float* __restrict__ lnb)
{
    const int lane = threadIdx.x & 63;
    const int wid = (blockIdx.x * 256 + threadIdx.x) >> 6;
    const int nw = gridDim.x * 4;
    const int ch_base = lane & 15;
    const int k0b = (lane >> 4) * 8;
    f16x8 bw[8][2];
#pragma unroll
    for (int t = 0; t < 8; ++t)
#pragma unroll
        for (int s = 0; s < 2; ++s)
            bw[t][s] = load_bfrag(W1, 128, t * 16 + ch_base, s * 32 + k0b);
    float b1_l[8];
#pragma unroll
    for (int t = 0; t < 8; ++t) b1_l[t] = b1[t * 16 + ch_base];
    for (int g = wid; g < NG; g += nw) {
        int n0 = g * 16;
        f16x8 a[2];
        build_ln_a(X, n0, lane, lng, lnb, a);
        f32x4 acc[8];
#pragma unroll
        for (int t = 0; t < 8; ++t) { acc[t][0] = 0.f; acc[t][1] = 0.f; acc[t][2] = 0.f; acc[t][3] = 0.f; }
#pragma unroll
        for (int t = 0; t < 8; ++t)
#pragma unroll
            for (int s = 0; s < 2; ++s)
                acc[t] = __builtin_amdgcn_mfma_f32_16x16x32_f16(a[s], bw[t][s], acc[t], 0, 0, 0);
        int rbase = n0 + (lane >> 4) * 4;
#pragma unroll
        for (int t = 0; t < 8; ++t) {
            int ch = t * 16 + ch_base;
#pragma unroll
            for (int j = 0; j < 4; ++j) {
                float v = acc[t][j] + b1_l[t];
                float o = 0.5f * v * (1.f + erff(v * 0.7071067811865476f));
                G16[(size_t)(rbase + j) * 128 + ch] = f2h(o);
            }
        }
    }
}

// ---------------- FFN2 (128->64) + residual into X (+ fused pool on last layer) ----------------
__global__ __launch_bounds__(256) void k_ffn2_m(const u16* __restrict__ G16, float* __restrict__ X,
    const float* __restrict__ W2, const float* __restrict__ b2,
    const int* __restrict__ batch, u32* __restrict__ pkeys, int dopool)
{
    const int lane = threadIdx.x & 63;
    const int wid = (blockIdx.x * 256 + threadIdx.x) >> 6;
    const int nw = gridDim.x * 4;
    const int ch_base = lane & 15;
    const int k0b = (lane >> 4) * 8;
    f16x8 bw[4][4];
#pragma unroll
    for (int t = 0; t < 4; ++t)
#pragma unroll
        for (int s = 0; s < 4; ++s)
            bw[t][s] = load_bfrag(W2, 64, t * 16 + ch_base, s * 32 + k0b);
    float b2_l[4];
#pragma unroll
    for (int t = 0; t < 4; ++t) b2_l[t] = b2[t * 16 + ch_base];
    for (int g = wid; g < NG; g += nw) {
        int n0 = g * 16;
        const u16* gp = G16 + (size_t)(n0 + ch_base) * 128 + k0b;
        f16x8 a0 = *(const f16x8*)(gp);
        f16x8 a1 = *(const f16x8*)(gp + 32);
        f16x8 a2 = *(const f16x8*)(gp + 64);
        f16x8 a3 = *(const f16x8*)(gp + 96);
        f32x4 acc[4];
#pragma unroll
        for (int t = 0; t < 4; ++t) { acc[t][0] = 0.f; acc[t][1] = 0.f; acc[t][2] = 0.f; acc[t][3] = 0.f; }
#pragma unroll
        for (int t = 0; t < 4; ++t) {
            acc[t] = __builtin_amdgcn_mfma_f32_16x16x32_f16(a0, bw[t][0], acc[t], 0, 0, 0);
            acc[t] = __builtin_amdgcn_mfma_f32_16x16x32_f16(a1, bw[t][1], acc[t], 0, 0, 0);
            acc[t] = __builtin_amdgcn_mfma_f32_16x16x32_f16(a2, bw[t][2], acc[t], 0, 0, 0);
            acc[t] = __builtin_amdgcn_mfma_f32_16x16x32_f16(a3, bw[t][3], acc[t], 0, 0, 0);
        }
        int rbase = n0 + (lane >> 4) * 4;
#pragma unroll
        for (int t = 0; t < 4; ++t) {
            int ch = t * 16 + ch_base;
#pragma unroll
            for (int j = 0; j < 4; ++j) {
                int n = rbase + j;
                float* dst = X + (size_t)n * 64 + ch;
                float v = *dst + acc[t][j] + b2_l[t];
                *dst = v;
                if (dopool) {
                    u32 u = __float_as_uint(v);
                    u32 key = (u >> 31) ? ~u : (u | 0x80000000u);
                    atomicMax(&pkeys[batch[n] * 64 + ch], key);
                }
            }
        }
    }
}

// ---------------- head: relu(pooled@Wo1+bo1)@Wo2+bo2, L2-normalize ----------------
__global__ __launch_bounds__(128) void k_head(const u32* __restrict__ pkeys,
    const float* __restrict__ Wo1, const float* __restrict__ bo1,
    const float* __restrict__ Wo2, const float* __restrict__ bo2,
    float* __restrict__ out)
{
    __shared__ float P[64];
    __shared__ float E1[128];
    __shared__ float wred[2];
    int b = blockIdx.x, t = threadIdx.x;
    if (t < 64) {
        u32 k = pkeys[b * 64 + t];
        float v = 0.f;
        if (k) v = (k >> 31) ? __uint_as_float(k ^ 0x80000000u) : __uint_as_float(~k);
        P[t] = v;
    }
    __syncthreads();
    float a = bo1[t];
#pragma unroll 8
    for (int k = 0; k < 64; ++k) a = fmaf(P[k], Wo1[k * 128 + t], a);
    E1[t] = fmaxf(a, 0.f);
    __syncthreads();
    float o = bo2[t];
#pragma unroll 8
    for (int k = 0; k < 128; ++k) o = fmaf(E1[k], Wo2[k * 128 + t], o);
    float ss = o * o;
#pragma unroll
    for (int off = 32; off; off >>= 1) ss += __shfl_xor(ss, off);
    if ((t & 63) == 0) wred[t >> 6] = ss;
    __syncthreads();
    float tot = wred[0] + wred[1];
    float nrm = fmaxf(sqrtf(tot), 1e-12f);
    out[b * 128 + t] = o / nrm;
}

// ---------------- launch ----------------
extern "C" void kernel_launch(void* const* d_in, const int* in_sizes, int n_in,
                              void* d_out, int out_size, void* d_ws, size_t ws_size,
                              hipStream_t stream)
{
    const float* x         = (const float*)d_in[0];
    const float* edge_attr = (const float*)d_in[1];
    const int* ei          = (const int*)d_in[2];
    const int* batch       = (const int*)d_in[3];
    const float* Win  = (const float*)d_in[4];
    const float* bin  = (const float*)d_in[5];
    const float* ln1g = (const float*)d_in[6];
    const float* ln1b = (const float*)d_in[7];
    const float* Wq   = (const float*)d_in[8];
    const float* bq   = (const float*)d_in[9];
    const float* Wk   = (const float*)d_in[10];
    const float* bk   = (const float*)d_in[11];
    const float* Wv   = (const float*)d_in[12];
    const float* bv   = (const float*)d_in[13];
    const float* We   = (const float*)d_in[14];
    const float* Wsk  = (const float*)d_in[15];
    const float* bsk  = (const float*)d_in[16];
    const float* Wbe  = (const float*)d_in[17];
    const float* ln2g = (const float*)d_in[18];
    const float* ln2b = (const float*)d_in[19];
    const float* W1   = (const float*)d_in[20];
    const float* b1   = (const float*)d_in[21];
    const float* W2   = (const float*)d_in[22];
    const float* b2   = (const float*)d_in[23];
    const float* Wo1  = (const float*)d_in[24];
    const float* bo1  = (const float*)d_in[25];
    const float* Wo2  = (const float*)d_in[26];
    const float* bo2  = (const float*)d_in[27];

    char* wsp = (char*)d_ws;
    size_t off = 0;
    auto alloc = [&](size_t bytes) { void* p = wsp + off; off = (off + bytes + 255) & ~(size_t)255; return p; };
    float*   X      = (float*)alloc((size_t)Nn * 64 * 4);
    float*   QX     = (float*)alloc((size_t)Nn * 128 * 4);
    u32*     KV     = (u32*)alloc((size_t)Nn * 64 * 4);
    u16*     G16    = (u16*)alloc((size_t)Nn * 128 * 2);
    int*     rowptr = (int*)alloc((size_t)(Nn + 1) * 4);
    int*     deg    = (int*)alloc((size_t)Nn * 4);
    int*     cursor = (int*)alloc((size_t)Nn * 4);
    int*     psum   = (int*)alloc((size_t)SCB * 4);
    int*     poff   = (int*)alloc((size_t)SCB * 4);
    int*     perm   = (int*)alloc((size_t)Ee * 4);
    int*     colsrc = (int*)alloc((size_t)Ee * 4);
    float4*  ea4    = (float4*)alloc((size_t)Ee * 16);
    u32*     pkeys  = (u32*)alloc((size_t)Bb * 64 * 4);

    hipMemsetAsync(deg, 0, (size_t)Nn * 4, stream);
    hipMemsetAsync(cursor, 0, (size_t)Nn * 4, stream);
    hipMemsetAsync(pkeys, 0, (size_t)Bb * 64 * 4, stream);

    k_input_proj<<<12500, 256, 0, stream>>>(x, Win, bin, X);
    k_hist<<<(Ee + 255) / 256, 256, 0, stream>>>(ei, deg);
    k_part<<<SCB, 256, 0, stream>>>(deg, psum);
    k_scanp<<<1, 256, 0, stream>>>(psum, poff);
    k_apply<<<SCB, 256, 0, stream>>>(deg, poff, rowptr);
    k_perm<<<(Ee + 255) / 256, 256, 0, stream>>>(ei, rowptr, cursor, perm);
    k_pack<<<(Ee + 255) / 256, 256, 0, stream>>>(ei, edge_attr, perm, colsrc, ea4);

    const int GB = 512;
    for (int l = 0; l < 3; ++l) {
        k_proj_kv<<<GB, 256, 0, stream>>>(X, KV, Wk + l * 4096, Wv + l * 4096,
            bk + l * 64, bv + l * 64, ln1g + l * 64, ln1b + l * 64);
        k_proj_qs<<<GB, 256, 0, stream>>>(X, QX, Wq + l * 4096, Wsk + l * 4096,
            bq + l * 64, bsk + l * 64, ln1g + l * 64, ln1b + l * 64);
        k_edge<<<Nn / 4, 256, 0, stream>>>(QX, KV, X, rowptr, colsrc, ea4,
            We + l * 256, Wbe + l * 192);
        k_ffn1_m<<<GB, 256, 0, stream>>>(X, G16, W1 + l * 8192, b1 + l * 128,
            ln2g + l * 64, ln2b + l * 64);
        k_ffn2_m<<<GB, 256, 0, stream>>>(G16, X, W2 + l * 8192, b2 + l * 64,
            batch, pkeys, (l == 2) ? 1 : 0);
    }
    k_head<<<Bb, 128, 0, stream>>>(pkeys, Wo1, bo1, Wo2, bo2, (float*)d_out);
}

// Round 8
// 494.044 us; speedup vs baseline: 1.0230x; 1.0230x over previous
//
#include <hip/hip_runtime.h>
#include <hip/hip_bf16.h>
#include <hip/hip_fp16.h>

#define Nn 50000
#define Ee 1000000
#define Bb 512
#define NG 3125   // 50000/16 node-row groups (exact)
#define SCB 196   // ceil(50000/256) scan blocks

typedef unsigned short u16;
typedef unsigned int u32;
typedef _Float16 f16;
typedef _Float16 f16x8 __attribute__((ext_vector_type(8)));
typedef float f32x4 __attribute__((ext_vector_type(4)));

__device__ __forceinline__ u16 f2h(float f) { return __half_as_ushort(__float2half(f)); }
__device__ __forceinline__ float h2f_lo(u32 kv) { return __half2float(__ushort_as_half((u16)(kv & 0xffff))); }
__device__ __forceinline__ float h2f_hi(u32 kv) { return __half2float(__ushort_as_half((u16)(kv >> 16))); }

__device__ __forceinline__ float fexp2(float x) {
    float r;
    asm("v_exp_f32 %0, %1" : "=v"(r) : "v"(x));
    return r;
}

// butterfly sum over each 16-lane group (one head) via DPP
__device__ __forceinline__ float red16(float x) {
    int t;
    t = __builtin_amdgcn_update_dpp(0, __float_as_int(x), 0xB1, 0xF, 0xF, true);   // quad_perm [1,0,3,2]
    x += __int_as_float(t);
    t = __builtin_amdgcn_update_dpp(0, __float_as_int(x), 0x4E, 0xF, 0xF, true);   // quad_perm [2,3,0,1]
    x += __int_as_float(t);
    t = __builtin_amdgcn_update_dpp(0, __float_as_int(x), 0x141, 0xF, 0xF, true);  // row_half_mirror
    x += __int_as_float(t);
    t = __builtin_amdgcn_update_dpp(0, __float_as_int(x), 0x140, 0xF, 0xF, true);  // row_mirror
    x += __int_as_float(t);
    return x;
}

// ---------------- input projection ----------------
__global__ __launch_bounds__(256) void k_input_proj(const float* __restrict__ x,
    const float* __restrict__ Win, const float* __restrict__ bin, float* __restrict__ X)
{
    __shared__ float W[8][64];
    __shared__ float bsh[64];
    int t = threadIdx.x;
    if (t < 64) bsh[t] = bin[t];
    for (int i = t; i < 512; i += 256) W[i >> 6][i & 63] = Win[i];
    __syncthreads();
    int gid = blockIdx.x * 256 + t;
    int n = gid >> 6, c = gid & 63;
    const float* xr = x + n * 8;
    float acc = bsh[c];
#pragma unroll
    for (int k = 0; k < 8; ++k) acc = fmaf(xr[k], W[k][c], acc);
    X[gid] = acc;
}

// ---------------- CSR build ----------------
__global__ __launch_bounds__(256) void k_hist(const int* __restrict__ ei, int* __restrict__ deg)
{
    int e = blockIdx.x * 256 + threadIdx.x;
    if (e < Ee) atomicAdd(&deg[ei[Ee + e]], 1);
}

__global__ __launch_bounds__(256) void k_part(const int* __restrict__ deg, int* __restrict__ psum)
{
    __shared__ int ws[4];
    int b = blockIdx.x, t = threadIdx.x;
    int idx = b * 256 + t;
    int v = (idx < Nn) ? deg[idx] : 0;
    int r = v;
#pragma unroll
    for (int off = 32; off; off >>= 1) r += __shfl_xor(r, off);
    if ((t & 63) == 0) ws[t >> 6] = r;
    __syncthreads();
    if (t == 0) psum[b] = ws[0] + ws[1] + ws[2] + ws[3];
}

__global__ __launch_bounds__(256) void k_scanp(const int* __restrict__ psum, int* __restrict__ poff)
{
    __shared__ int ws[4];
    int t = threadIdx.x, lane = t & 63, w = t >> 6;
    int v = (t < SCB) ? psum[t] : 0;
    int s = v;
#pragma unroll
    for (int off = 1; off < 64; off <<= 1) {
        int u = __shfl_up(s, off);
        if (lane >= off) s += u;
    }
    if (lane == 63) ws[w] = s;
    __syncthreads();
    if (t == 0) { int a = 0; for (int i = 0; i < 4; ++i) { a += ws[i]; ws[i] = a; } }
    __syncthreads();
    int incl = s + (w ? ws[w - 1] : 0);
    if (t < SCB) poff[t] = incl - v;
}

__global__ __launch_bounds__(256) void k_apply(const int* __restrict__ deg, const int* __restrict__ poff,
    int* __restrict__ rowptr)
{
    __shared__ int ws[4];
    int b = blockIdx.x, t = threadIdx.x, lane = t & 63, w = t >> 6;
    int idx = b * 256 + t;
    int v = (idx < Nn) ? deg[idx] : 0;
    int s = v;
#pragma unroll
    for (int off = 1; off < 64; off <<= 1) {
        int u = __shfl_up(s, off);
        if (lane >= off) s += u;
    }
    if (lane == 63) ws[w] = s;
    __syncthreads();
    if (t == 0) { int a = 0; for (int i = 0; i < 4; ++i) { a += ws[i]; ws[i] = a; } }
    __syncthreads();
    int incl = s + (w ? ws[w - 1] : 0) + poff[b];
    if (idx < Nn) rowptr[idx + 1] = incl;
    if (b == 0 && t == 0) rowptr[0] = 0;
}

__global__ __launch_bounds__(256) void k_scatter(const int* __restrict__ ei, const float* __restrict__ eattr,
    const int* __restrict__ rowptr, int* __restrict__ cursor, int* __restrict__ colsrc,
    float4* __restrict__ ea4)
{
    int e = blockIdx.x * 256 + threadIdx.x;
    if (e >= Ee) return;
    int d = ei[Ee + e];
    int pos = rowptr[d] + atomicAdd(&cursor[d], 1);
    colsrc[pos] = ei[e];
    ea4[pos] = *(const float4*)(eattr + (size_t)e * 4);
}

// ---------------- MFMA helpers ----------------
__device__ __forceinline__ f16x8 load_bfrag(const float* __restrict__ W, int NC, int col, int k0)
{
    f16x8 b;
    const float* wp = W + (size_t)k0 * NC + col;
#pragma unroll
    for (int i = 0; i < 8; ++i) b[i] = (f16)wp[i * NC];
    return b;
}

__device__ __forceinline__ void build_ln_a(const float* __restrict__ X, int n0, int lane,
    const float* __restrict__ lng, const float* __restrict__ lnb, f16x8* a)
{
    const int r = lane & 15, c = lane >> 4;
    const float* xp = X + (size_t)(n0 + r) * 64 + c * 8;
    float4 x0 = *(const float4*)(xp);
    float4 x1 = *(const float4*)(xp + 4);
    float4 x2 = *(const float4*)(xp + 32);
    float4 x3 = *(const float4*)(xp + 36);
    float xs[16] = {x0.x, x0.y, x0.z, x0.w, x1.x, x1.y, x1.z, x1.w,
                    x2.x, x2.y, x2.z, x2.w, x3.x, x3.y, x3.z, x3.w};
    float s = 0.f, s2 = 0.f;
#pragma unroll
    for (int i = 0; i < 16; ++i) { s += xs[i]; s2 = fmaf(xs[i], xs[i], s2); }
    s += __shfl_xor(s, 16);  s += __shfl_xor(s, 32);
    s2 += __shfl_xor(s2, 16); s2 += __shfl_xor(s2, 32);
    float mu = s * 0.015625f;
    float var = s2 * 0.015625f - mu * mu;
    float rstd = rsqrtf(fmaxf(var, 0.f) + 1e-5f);
    const float* gp = lng + c * 8;
    const float* bp = lnb + c * 8;
    float4 g0 = *(const float4*)(gp),      g1 = *(const float4*)(gp + 4);
    float4 g2 = *(const float4*)(gp + 32), g3 = *(const float4*)(gp + 36);
    float4 b0 = *(const float4*)(bp),      b1 = *(const float4*)(bp + 4);
    float4 b2 = *(const float4*)(bp + 32), b3 = *(const float4*)(bp + 36);
    float gs[16] = {g0.x, g0.y, g0.z, g0.w, g1.x, g1.y, g1.z, g1.w,
                    g2.x, g2.y, g2.z, g2.w, g3.x, g3.y, g3.z, g3.w};
    float bs[16] = {b0.x, b0.y, b0.z, b0.w, b1.x, b1.y, b1.z, b1.w,
                    b2.x, b2.y, b2.z, b2.w, b3.x, b3.y, b3.z, b3.w};
#pragma unroll
    for (int i = 0; i < 16; ++i) {
        float h = (xs[i] - mu) * rstd * gs[i] + bs[i];
        a[i >> 3][i & 7] = (f16)h;
    }
}

// ---------------- fused LN1 + Q,Skip + K,V projections (two weight phases) ----------------
__global__ __launch_bounds__(256) void k_proj(const float* __restrict__ X,
    float* __restrict__ QX, u32* __restrict__ KV,
    const float* __restrict__ Wq, const float* __restrict__ Ws,
    const float* __restrict__ Wk, const float* __restrict__ Wv,
    const float* __restrict__ bq, const float* __restrict__ bs_,
    const float* __restrict__ bk, const float* __restrict__ bv,
    const float* __restrict__ lng, const float* __restrict__ lnb)
{
    const int lane = threadIdx.x & 63;
    const int wid = (blockIdx.x * 256 + threadIdx.x) >> 6;
    const int nw = gridDim.x * 4;
    const int ch_base = lane & 15;
    const int k0b = (lane >> 4) * 8;
    float bq_l[4], bs_l[4], bk_l[4], bv_l[4];
#pragma unroll
    for (int t = 0; t < 4; ++t) {
        bq_l[t] = bq[t * 16 + ch_base]; bs_l[t] = bs_[t * 16 + ch_base];
        bk_l[t] = bk[t * 16 + ch_base]; bv_l[t] = bv[t * 16 + ch_base];
    }
    for (int g = wid; g < NG; g += nw) {
        int n0 = g * 16;
        f16x8 a[2];
        build_ln_a(X, n0, lane, lng, lnb, a);
        int rbase = n0 + (lane >> 4) * 4;
        // phase 1: Q | Skip -> QX
        {
            f16x8 bw[8][2];
#pragma unroll
            for (int t = 0; t < 4; ++t)
#pragma unroll
                for (int s = 0; s < 2; ++s) {
                    bw[t][s]     = load_bfrag(Wq, 64, t * 16 + ch_base, s * 32 + k0b);
                    bw[t + 4][s] = load_bfrag(Ws, 64, t * 16 + ch_base, s * 32 + k0b);
                }
            f32x4 acc[8];
#pragma unroll
            for (int t = 0; t < 8; ++t) { acc[t][0] = 0.f; acc[t][1] = 0.f; acc[t][2] = 0.f; acc[t][3] = 0.f; }
#pragma unroll
            for (int t = 0; t < 8; ++t)
#pragma unroll
                for (int s = 0; s < 2; ++s)
                    acc[t] = __builtin_amdgcn_mfma_f32_16x16x32_f16(a[s], bw[t][s], acc[t], 0, 0, 0);
#pragma unroll
            for (int t = 0; t < 4; ++t) {
                int ch = t * 16 + ch_base;
#pragma unroll
                for (int j = 0; j < 4; ++j) {
                    float* dst = QX + (size_t)(rbase + j) * 128;
                    dst[ch] = acc[t][j] + bq_l[t];
                    dst[64 + ch] = acc[t + 4][j] + bs_l[t];
                }
            }
        }
        // phase 2: K | V -> packed f16 KV
        {
            f16x8 bw[8][2];
#pragma unroll
            for (int t = 0; t < 4; ++t)
#pragma unroll
                for (int s = 0; s < 2; ++s) {
                    bw[t][s]     = load_bfrag(Wk, 64, t * 16 + ch_base, s * 32 + k0b);
                    bw[t + 4][s] = load_bfrag(Wv, 64, t * 16 + ch_base, s * 32 + k0b);
                }
            f32x4 acc[8];
#pragma unroll
            for (int t = 0; t < 8; ++t) { acc[t][0] = 0.f; acc[t][1] = 0.f; acc[t][2] = 0.f; acc[t][3] = 0.f; }
#pragma unroll
            for (int t = 0; t < 8; ++t)
#pragma unroll
                for (int s = 0; s < 2; ++s)
                    acc[t] = __builtin_amdgcn_mfma_f32_16x16x32_f16(a[s], bw[t][s], acc[t], 0, 0, 0);
#pragma unroll
            for (int t = 0; t < 4; ++t) {
                int ch = t * 16 + ch_base;
#pragma unroll
                for (int j = 0; j < 4; ++j) {
                    u32 lo = f2h(acc[t][j] + bk_l[t]);
                    u32 hi = f2h(acc[t + 4][j] + bv_l[t]);
                    KV[(size_t)(rbase + j) * 64 + ch] = (hi << 16) | lo;
                }
            }
        }
    }
}

// ---------------- edge attention (unchanged math) ----------------
__global__ __launch_bounds__(256) void k_edge(
    const float* __restrict__ QX, const u32* __restrict__ KV, float* __restrict__ X,
    const int* __restrict__ rowptr, const int* __restrict__ colsrc,
    const float4* __restrict__ ea4,
    const float* __restrict__ We, const float* __restrict__ Wbeta)
{
    const float SCL = 0.25f * 1.4426950408889634f;
    int lane = threadIdx.x & 63;
    int node = blockIdx.x * 4 + (threadIdx.x >> 6);
    if (node >= Nn) return;
    float we0 = We[lane], we1 = We[64 + lane];
    float we2 = We[128 + lane], we3 = We[192 + lane];
    float wbA = Wbeta[lane] + Wbeta[128 + lane];
    float wbB = Wbeta[64 + lane] - Wbeta[128 + lane];
    const float* qrow = QX + (size_t)node * 128;
    float q = qrow[lane] * SCL;
    float xr = qrow[64 + lane];
    int jb = rowptr[node], je = rowptr[node + 1];
    float l0 = 0.f, l1 = 0.f, a0 = 0.f, a1 = 0.f;
    int j = jb;
    for (; j + 3 < je; j += 4) {
        int src[4]; float4 eb[4]; u32 kv[4];
#pragma unroll
        for (int c = 0; c < 4; ++c) src[c] = colsrc[j + c];
#pragma unroll
        for (int c = 0; c < 4; ++c) kv[c] = KV[(src[c] << 6) | lane];
#pragma unroll
        for (int c = 0; c < 4; ++c) eb[c] = ea4[j + c];
        float pe[4], ve[4];
#pragma unroll
        for (int c = 0; c < 4; ++c) {
            float e = we0 * eb[c].x;
            e = fmaf(we1, eb[c].y, e); e = fmaf(we2, eb[c].z, e); e = fmaf(we3, eb[c].w, e);
            float ke = h2f_lo(kv[c]) + e;
            ve[c] = h2f_hi(kv[c]) + e;
            float p = red16(q * ke);
            pe[c] = fexp2(p);
        }
        l0 += pe[0]; l1 += pe[1];
        a0 = fmaf(pe[0], ve[0], a0); a1 = fmaf(pe[1], ve[1], a1);
        l0 += pe[2]; l1 += pe[3];
        a0 = fmaf(pe[2], ve[2], a0); a1 = fmaf(pe[3], ve[3], a1);
    }
    for (; j < je; ++j) {
        int s0 = colsrc[j];
        float4 eb0 = ea4[j];
        u32 kv0 = KV[(s0 << 6) | lane];
        float e0 = we0 * eb0.x;
        e0 = fmaf(we1, eb0.y, e0); e0 = fmaf(we2, eb0.z, e0); e0 = fmaf(we3, eb0.w, e0);
        float ke0 = h2f_lo(kv0) + e0, ve0 = h2f_hi(kv0) + e0;
        float p0 = red16(q * ke0);
        float pe0 = fexp2(p0);
        l0 += pe0;
        a0 = fmaf(pe0, ve0, a0);
    }
    float lsum = l0 + l1;
    float acc = a0 + a1;
    float outv = acc / (lsum + 1e-16f);
    float tb = outv * wbA + xr * wbB;
#pragma unroll
    for (int off = 32; off; off >>= 1) tb += __shfl_xor(tb, off);
    float beta = 1.f / (1.f + __expf(-tb));
    float res = beta * xr + (1.f - beta) * outv;
    X[(size_t)node * 64 + lane] += res;
}

// ---------------- fused LN2 + FFN1 + GELU + FFN2 + residual (+pool) ----------------
// per-wave LDS transpose of the 16x128 hidden tile; row stride 136 u16 = 272B (16B-aligned, bank-stride 4)
__global__ __launch_bounds__(256) void k_ffn(const float* __restrict__ X_in, float* __restrict__ X,
    const float* __restrict__ W1, const float* __restrict__ b1,
    const float* __restrict__ W2, const float* __restrict__ b2,
    const float* __restrict__ lng, const float* __restrict__ lnb,
    const int* __restrict__ batch, u32* __restrict__ pkeys, int dopool)
{
    __shared__ u16 lds[4][16][136];
    const int lane = threadIdx.x & 63;
    const int wloc = threadIdx.x >> 6;
    const int wid = (blockIdx.x * 256 + threadIdx.x) >> 6;
    const int nw = gridDim.x * 4;
    const int ch_base = lane & 15;
    const int k0b = (lane >> 4) * 8;
    float b1_l[8];
#pragma unroll
    for (int t = 0; t < 8; ++t) b1_l[t] = b1[t * 16 + ch_base];
    float b2_l[4];
#pragma unroll
    for (int t = 0; t < 4; ++t) b2_l[t] = b2[t * 16 + ch_base];
    for (int g = wid; g < NG; g += nw) {
        int n0 = g * 16;
        f16x8 a[2];
        build_ln_a(X_in, n0, lane, lng, lnb, a);
        int rbase = n0 + (lane >> 4) * 4;
        // FFN1: 64 -> 128, + bias + gelu, deposit transposed into LDS
        {
            f16x8 bw[8][2];
#pragma unroll
            for (int t = 0; t < 8; ++t)
#pragma unroll
                for (int s = 0; s < 2; ++s)
                    bw[t][s] = load_bfrag(W1, 128, t * 16 + ch_base, s * 32 + k0b);
            f32x4 acc[8];
#pragma unroll
            for (int t = 0; t < 8; ++t) { acc[t][0] = 0.f; acc[t][1] = 0.f; acc[t][2] = 0.f; acc[t][3] = 0.f; }
#pragma unroll
            for (int t = 0; t < 8; ++t)
#pragma unroll
                for (int s = 0; s < 2; ++s)
                    acc[t] = __builtin_amdgcn_mfma_f32_16x16x32_f16(a[s], bw[t][s], acc[t], 0, 0, 0);
            const int rloc = (lane >> 4) * 4;
#pragma unroll
            for (int t = 0; t < 8; ++t) {
                int ch = t * 16 + ch_base;
#pragma unroll
                for (int j = 0; j < 4; ++j) {
                    float v = acc[t][j] + b1_l[t];
                    float o = 0.5f * v * (1.f + erff(v * 0.7071067811865476f));
                    lds[wloc][rloc + j][ch] = f2h(o);
                }
            }
        }
        // FFN2: 128 -> 64, read A-fragments from LDS (wave-local, compiler inserts lgkmcnt)
        {
            f16x8 ga[4];
#pragma unroll
            for (int s = 0; s < 4; ++s)
                ga[s] = *(const f16x8*)&lds[wloc][ch_base][s * 32 + k0b];
            f16x8 bw[4][4];
#pragma unroll
            for (int t = 0; t < 4; ++t)
#pragma unroll
                for (int s = 0; s < 4; ++s)
                    bw[t][s] = load_bfrag(W2, 64, t * 16 + ch_base, s * 32 + k0b);
            f32x4 acc[4];
#pragma unroll
            for (int t = 0; t < 4; ++t) { acc[t][0] = 0.f; acc[t][1] = 0.f; acc[t][2] = 0.f; acc[t][3] = 0.f; }
#pragma unroll
            for (int t = 0; t < 4; ++t)
#pragma unroll
                for (int s = 0; s < 4; ++s)
                    acc[t] = __builtin_amdgcn_mfma_f32_16x16x32_f16(ga[s], bw[t][s], acc[t], 0, 0, 0);
#pragma unroll
            for (int t = 0; t < 4; ++t) {
                int ch = t * 16 + ch_base;
#pragma unroll
                for (int j = 0; j < 4; ++j) {
                    int n = rbase + j;
                    float* dst = X + (size_t)n * 64 + ch;
                    float v = *dst + acc[t][j] + b2_l[t];
                    *dst = v;
                    if (dopool) {
                        u32 u = __float_as_uint(v);
                        u32 key = (u >> 31) ? ~u : (u | 0x80000000u);
                        atomicMax(&pkeys[batch[n] * 64 + ch], key);
                    }
                }
            }
        }
    }
}

// ---------------- head ----------------
__global__ __launch_bounds__(128) void k_head(const u32* __restrict__ pkeys,
    const float* __restrict__ Wo1, const float* __restrict__ bo1,
    const float* __restrict__ Wo2, const float* __restrict__ bo2,
    float* __restrict__ out)
{
    __shared__ float P[64];
    __shared__ float E1[128];
    __shared__ float wred[2];
    int b = blockIdx.x, t = threadIdx.x;
    if (t < 64) {
        u32 k = pkeys[b * 64 + t];
        float v = 0.f;
        if (k) v = (k >> 31) ? __uint_as_float(k ^ 0x80000000u) : __uint_as_float(~k);
        P[t] = v;
    }
    __syncthreads();
    float a = bo1[t];
#pragma unroll 8
    for (int k = 0; k < 64; ++k) a = fmaf(P[k], Wo1[k * 128 + t], a);
    E1[t] = fmaxf(a, 0.f);
    __syncthreads();
    float o = bo2[t];
#pragma unroll 8
    for (int k = 0; k < 128; ++k) o = fmaf(E1[k], Wo2[k * 128 + t], o);
    float ss = o * o;
#pragma unroll
    for (int off = 32; off; off >>= 1) ss += __shfl_xor(ss, off);
    if ((t & 63) == 0) wred[t >> 6] = ss;
    __syncthreads();
    float tot = wred[0] + wred[1];
    float nrm = fmaxf(sqrtf(tot), 1e-12f);
    out[b * 128 + t] = o / nrm;
}

// ---------------- launch ----------------
extern "C" void kernel_launch(void* const* d_in, const int* in_sizes, int n_in,
                              void* d_out, int out_size, void* d_ws, size_t ws_size,
                              hipStream_t stream)
{
    const float* x         = (const float*)d_in[0];
    const float* edge_attr = (const float*)d_in[1];
    const int* ei          = (const int*)d_in[2];
    const int* batch       = (const int*)d_in[3];
    const float* Win  = (const float*)d_in[4];
    const float* bin  = (const float*)d_in[5];
    const float* ln1g = (const float*)d_in[6];
    const float* ln1b = (const float*)d_in[7];
    const float* Wq   = (const float*)d_in[8];
    const float* bq   = (const float*)d_in[9];
    const float* Wk   = (const float*)d_in[10];
    const float* bk   = (const float*)d_in[11];
    const float* Wv   = (const float*)d_in[12];
    const float* bv   = (const float*)d_in[13];
    const float* We   = (const float*)d_in[14];
    const float* Wsk  = (const float*)d_in[15];
    const float* bsk  = (const float*)d_in[16];
    const float* Wbe  = (const float*)d_in[17];
    const float* ln2g = (const float*)d_in[18];
    const float* ln2b = (const float*)d_in[19];
    const float* W1   = (const float*)d_in[20];
    const float* b1   = (const float*)d_in[21];
    const float* W2   = (const float*)d_in[22];
    const float* b2   = (const float*)d_in[23];
    const float* Wo1  = (const float*)d_in[24];
    const float* bo1  = (const float*)d_in[25];
    const float* Wo2  = (const float*)d_in[26];
    const float* bo2  = (const float*)d_in[27];

    char* wsp = (char*)d_ws;
    size_t off = 0;
    auto alloc = [&](size_t bytes) { void* p = wsp + off; off = (off + bytes + 255) & ~(size_t)255; return p; };
    float*   X      = (float*)alloc((size_t)Nn * 64 * 4);
    float*   QX     = (float*)alloc((size_t)Nn * 128 * 4);
    u32*     KV     = (u32*)alloc((size_t)Nn * 64 * 4);
    int*     rowptr = (int*)alloc((size_t)(Nn + 1) * 4);
    int*     deg    = (int*)alloc((size_t)Nn * 4);
    int*     cursor = (int*)alloc((size_t)Nn * 4);
    int*     psum   = (int*)alloc((size_t)SCB * 4);
    int*     poff   = (int*)alloc((size_t)SCB * 4);
    int*     colsrc = (int*)alloc((size_t)Ee * 4);
    float4*  ea4    = (float4*)alloc((size_t)Ee * 16);
    u32*     pkeys  = (u32*)alloc((size_t)Bb * 64 * 4);

    hipMemsetAsync(deg, 0, (size_t)Nn * 4, stream);
    hipMemsetAsync(cursor, 0, (size_t)Nn * 4, stream);
    hipMemsetAsync(pkeys, 0, (size_t)Bb * 64 * 4, stream);

    k_input_proj<<<12500, 256, 0, stream>>>(x, Win, bin, X);
    k_hist<<<(Ee + 255) / 256, 256, 0, stream>>>(ei, deg);
    k_part<<<SCB, 256, 0, stream>>>(deg, psum);
    k_scanp<<<1, 256, 0, stream>>>(psum, poff);
    k_apply<<<SCB, 256, 0, stream>>>(deg, poff, rowptr);
    k_scatter<<<(Ee + 255) / 256, 256, 0, stream>>>(ei, edge_attr, rowptr, cursor, colsrc, ea4);

    const int GB = 512;
    for (int l = 0; l < 3; ++l) {
        k_proj<<<GB, 256, 0, stream>>>(X, QX, KV,
            Wq + l * 4096, Wsk + l * 4096, Wk + l * 4096, Wv + l * 4096,
            bq + l * 64, bsk + l * 64, bk + l * 64, bv + l * 64,
            ln1g + l * 64, ln1b + l * 64);
        k_edge<<<Nn / 4, 256, 0, stream>>>(QX, KV, X, rowptr, colsrc, ea4,
            We + l * 256, Wbe + l * 192);
        k_ffn<<<GB, 256, 0, stream>>>(X, X, W1 + l * 8192, b1 + l * 128,
            W2 + l * 8192, b2 + l * 64, ln2g + l * 64, ln2b + l * 64,
            batch, pkeys, (l == 2) ? 1 : 0);
    }
    k_head<<<Bb, 128, 0, stream>>>(pkeys, Wo1, bo1, Wo2, bo2, (float*)d_out);
}

// Round 9
// 482.271 us; speedup vs baseline: 1.0480x; 1.0244x over previous
//
#include <hip/hip_runtime.h>
#include <hip/hip_bf16.h>
#include <hip/hip_fp16.h>

#define Nn 50000
#define Ee 1000000
#define Bb 512
#define NG 3125   // 50000/16 node-row groups (exact)
#define SCB 196   // ceil(50000/256) scan blocks
#define GB 782    // dense-kernel grid: 782*4=3128 waves >= 3125 groups (1 group/wave)

typedef unsigned short u16;
typedef unsigned int u32;
typedef _Float16 f16;
typedef _Float16 f16x8 __attribute__((ext_vector_type(8)));
typedef float f32x4 __attribute__((ext_vector_type(4)));

__device__ __forceinline__ u16 f2h(float f) { return __half_as_ushort(__float2half(f)); }
__device__ __forceinline__ float h2f_lo(u32 kv) { return __half2float(__ushort_as_half((u16)(kv & 0xffff))); }
__device__ __forceinline__ float h2f_hi(u32 kv) { return __half2float(__ushort_as_half((u16)(kv >> 16))); }

__device__ __forceinline__ float fexp2(float x) {
    float r;
    asm("v_exp_f32 %0, %1" : "=v"(r) : "v"(x));
    return r;
}

// butterfly sum over each 16-lane group (one head) via DPP
__device__ __forceinline__ float red16(float x) {
    int t;
    t = __builtin_amdgcn_update_dpp(0, __float_as_int(x), 0xB1, 0xF, 0xF, true);   // quad_perm [1,0,3,2]
    x += __int_as_float(t);
    t = __builtin_amdgcn_update_dpp(0, __float_as_int(x), 0x4E, 0xF, 0xF, true);   // quad_perm [2,3,0,1]
    x += __int_as_float(t);
    t = __builtin_amdgcn_update_dpp(0, __float_as_int(x), 0x141, 0xF, 0xF, true);  // row_half_mirror
    x += __int_as_float(t);
    t = __builtin_amdgcn_update_dpp(0, __float_as_int(x), 0x140, 0xF, 0xF, true);  // row_mirror
    x += __int_as_float(t);
    return x;
}

// ---------------- input projection ----------------
__global__ __launch_bounds__(256) void k_input_proj(const float* __restrict__ x,
    const float* __restrict__ Win, const float* __restrict__ bin, float* __restrict__ X)
{
    __shared__ float W[8][64];
    __shared__ float bsh[64];
    int t = threadIdx.x;
    if (t < 64) bsh[t] = bin[t];
    for (int i = t; i < 512; i += 256) W[i >> 6][i & 63] = Win[i];
    __syncthreads();
    int gid = blockIdx.x * 256 + t;
    int n = gid >> 6, c = gid & 63;
    const float* xr = x + n * 8;
    float acc = bsh[c];
#pragma unroll
    for (int k = 0; k < 8; ++k) acc = fmaf(xr[k], W[k][c], acc);
    X[gid] = acc;
}

// ---------------- CSR build ----------------
__global__ __launch_bounds__(256) void k_hist(const int* __restrict__ ei, int* __restrict__ deg)
{
    int e = blockIdx.x * 256 + threadIdx.x;
    if (e < Ee) atomicAdd(&deg[ei[Ee + e]], 1);
}

__global__ __launch_bounds__(256) void k_part(const int* __restrict__ deg, int* __restrict__ psum)
{
    __shared__ int ws[4];
    int b = blockIdx.x, t = threadIdx.x;
    int idx = b * 256 + t;
    int v = (idx < Nn) ? deg[idx] : 0;
    int r = v;
#pragma unroll
    for (int off = 32; off; off >>= 1) r += __shfl_xor(r, off);
    if ((t & 63) == 0) ws[t >> 6] = r;
    __syncthreads();
    if (t == 0) psum[b] = ws[0] + ws[1] + ws[2] + ws[3];
}

__global__ __launch_bounds__(256) void k_scanp(const int* __restrict__ psum, int* __restrict__ poff)
{
    __shared__ int ws[4];
    int t = threadIdx.x, lane = t & 63, w = t >> 6;
    int v = (t < SCB) ? psum[t] : 0;
    int s = v;
#pragma unroll
    for (int off = 1; off < 64; off <<= 1) {
        int u = __shfl_up(s, off);
        if (lane >= off) s += u;
    }
    if (lane == 63) ws[w] = s;
    __syncthreads();
    if (t == 0) { int a = 0; for (int i = 0; i < 4; ++i) { a += ws[i]; ws[i] = a; } }
    __syncthreads();
    int incl = s + (w ? ws[w - 1] : 0);
    if (t < SCB) poff[t] = incl - v;
}

__global__ __launch_bounds__(256) void k_apply(const int* __restrict__ deg, const int* __restrict__ poff,
    int* __restrict__ rowptr)
{
    __shared__ int ws[4];
    int b = blockIdx.x, t = threadIdx.x, lane = t & 63, w = t >> 6;
    int idx = b * 256 + t;
    int v = (idx < Nn) ? deg[idx] : 0;
    int s = v;
#pragma unroll
    for (int off = 1; off < 64; off <<= 1) {
        int u = __shfl_up(s, off);
        if (lane >= off) s += u;
    }
    if (lane == 63) ws[w] = s;
    __syncthreads();
    if (t == 0) { int a = 0; for (int i = 0; i < 4; ++i) { a += ws[i]; ws[i] = a; } }
    __syncthreads();
    int incl = s + (w ? ws[w - 1] : 0) + poff[b];
    if (idx < Nn) rowptr[idx + 1] = incl;
    if (b == 0 && t == 0) rowptr[0] = 0;
}

__global__ __launch_bounds__(256) void k_scatter(const int* __restrict__ ei, const float* __restrict__ eattr,
    const int* __restrict__ rowptr, int* __restrict__ cursor, int* __restrict__ colsrc,
    float4* __restrict__ ea4)
{
    int e = blockIdx.x * 256 + threadIdx.x;
    if (e >= Ee) return;
    int d = ei[Ee + e];
    int pos = rowptr[d] + atomicAdd(&cursor[d], 1);
    colsrc[pos] = ei[e];
    ea4[pos] = *(const float4*)(eattr + (size_t)e * 4);
}

// ---------------- MFMA helpers ----------------
__device__ __forceinline__ f16x8 load_bfrag(const float* __restrict__ W, int NC, int col, int k0)
{
    f16x8 b;
    const float* wp = W + (size_t)k0 * NC + col;
#pragma unroll
    for (int i = 0; i < 8; ++i) b[i] = (f16)wp[i * NC];
    return b;
}

__device__ __forceinline__ void build_ln_a(const float* __restrict__ X, int n0, int lane,
    const float* __restrict__ lng, const float* __restrict__ lnb, f16x8* a)
{
    const int r = lane & 15, c = lane >> 4;
    const float* xp = X + (size_t)(n0 + r) * 64 + c * 8;
    float4 x0 = *(const float4*)(xp);
    float4 x1 = *(const float4*)(xp + 4);
    float4 x2 = *(const float4*)(xp + 32);
    float4 x3 = *(const float4*)(xp + 36);
    float xs[16] = {x0.x, x0.y, x0.z, x0.w, x1.x, x1.y, x1.z, x1.w,
                    x2.x, x2.y, x2.z, x2.w, x3.x, x3.y, x3.z, x3.w};
    float s = 0.f, s2 = 0.f;
#pragma unroll
    for (int i = 0; i < 16; ++i) { s += xs[i]; s2 = fmaf(xs[i], xs[i], s2); }
    s += __shfl_xor(s, 16);  s += __shfl_xor(s, 32);
    s2 += __shfl_xor(s2, 16); s2 += __shfl_xor(s2, 32);
    float mu = s * 0.015625f;
    float var = s2 * 0.015625f - mu * mu;
    float rstd = rsqrtf(fmaxf(var, 0.f) + 1e-5f);
    const float* gp = lng + c * 8;
    const float* bp = lnb + c * 8;
    float4 g0 = *(const float4*)(gp),      g1 = *(const float4*)(gp + 4);
    float4 g2 = *(const float4*)(gp + 32), g3 = *(const float4*)(gp + 36);
    float4 b0 = *(const float4*)(bp),      b1 = *(const float4*)(bp + 4);
    float4 b2 = *(const float4*)(bp + 32), b3 = *(const float4*)(bp + 36);
    float gs[16] = {g0.x, g0.y, g0.z, g0.w, g1.x, g1.y, g1.z, g1.w,
                    g2.x, g2.y, g2.z, g2.w, g3.x, g3.y, g3.z, g3.w};
    float bs[16] = {b0.x, b0.y, b0.z, b0.w, b1.x, b1.y, b1.z, b1.w,
                    b2.x, b2.y, b2.z, b2.w, b3.x, b3.y, b3.z, b3.w};
#pragma unroll
    for (int i = 0; i < 16; ++i) {
        float h = (xs[i] - mu) * rstd * gs[i] + bs[i];
        a[i >> 3][i & 7] = (f16)h;
    }
}

// ---------------- fused LN1 + Q,Skip + K,V projections (two weight phases) ----------------
__global__ __launch_bounds__(256) void k_proj(const float* __restrict__ X,
    float* __restrict__ QX, u32* __restrict__ KV,
    const float* __restrict__ Wq, const float* __restrict__ Ws,
    const float* __restrict__ Wk, const float* __restrict__ Wv,
    const float* __restrict__ bq, const float* __restrict__ bs_,
    const float* __restrict__ bk, const float* __restrict__ bv,
    const float* __restrict__ lng, const float* __restrict__ lnb)
{
    const int lane = threadIdx.x & 63;
    const int wid = (blockIdx.x * 256 + threadIdx.x) >> 6;
    const int nw = gridDim.x * 4;
    const int ch_base = lane & 15;
    const int k0b = (lane >> 4) * 8;
    float bq_l[4], bs_l[4], bk_l[4], bv_l[4];
#pragma unroll
    for (int t = 0; t < 4; ++t) {
        bq_l[t] = bq[t * 16 + ch_base]; bs_l[t] = bs_[t * 16 + ch_base];
        bk_l[t] = bk[t * 16 + ch_base]; bv_l[t] = bv[t * 16 + ch_base];
    }
    for (int g = wid; g < NG; g += nw) {
        int n0 = g * 16;
        f16x8 a[2];
        build_ln_a(X, n0, lane, lng, lnb, a);
        int rbase = n0 + (lane >> 4) * 4;
        // phase 1: Q | Skip -> QX
        {
            f16x8 bw[8][2];
#pragma unroll
            for (int t = 0; t < 4; ++t)
#pragma unroll
                for (int s = 0; s < 2; ++s) {
                    bw[t][s]     = load_bfrag(Wq, 64, t * 16 + ch_base, s * 32 + k0b);
                    bw[t + 4][s] = load_bfrag(Ws, 64, t * 16 + ch_base, s * 32 + k0b);
                }
            f32x4 acc[8];
#pragma unroll
            for (int t = 0; t < 8; ++t) { acc[t][0] = 0.f; acc[t][1] = 0.f; acc[t][2] = 0.f; acc[t][3] = 0.f; }
#pragma unroll
            for (int t = 0; t < 8; ++t)
#pragma unroll
                for (int s = 0; s < 2; ++s)
                    acc[t] = __builtin_amdgcn_mfma_f32_16x16x32_f16(a[s], bw[t][s], acc[t], 0, 0, 0);
#pragma unroll
            for (int t = 0; t < 4; ++t) {
                int ch = t * 16 + ch_base;
#pragma unroll
                for (int j = 0; j < 4; ++j) {
                    float* dst = QX + (size_t)(rbase + j) * 128;
                    dst[ch] = acc[t][j] + bq_l[t];
                    dst[64 + ch] = acc[t + 4][j] + bs_l[t];
                }
            }
        }
        // phase 2: K | V -> packed f16 KV
        {
            f16x8 bw[8][2];
#pragma unroll
            for (int t = 0; t < 4; ++t)
#pragma unroll
                for (int s = 0; s < 2; ++s) {
                    bw[t][s]     = load_bfrag(Wk, 64, t * 16 + ch_base, s * 32 + k0b);
                    bw[t + 4][s] = load_bfrag(Wv, 64, t * 16 + ch_base, s * 32 + k0b);
                }
            f32x4 acc[8];
#pragma unroll
            for (int t = 0; t < 8; ++t) { acc[t][0] = 0.f; acc[t][1] = 0.f; acc[t][2] = 0.f; acc[t][3] = 0.f; }
#pragma unroll
            for (int t = 0; t < 8; ++t)
#pragma unroll
                for (int s = 0; s < 2; ++s)
                    acc[t] = __builtin_amdgcn_mfma_f32_16x16x32_f16(a[s], bw[t][s], acc[t], 0, 0, 0);
#pragma unroll
            for (int t = 0; t < 4; ++t) {
                int ch = t * 16 + ch_base;
#pragma unroll
                for (int j = 0; j < 4; ++j) {
                    u32 lo = f2h(acc[t][j] + bk_l[t]);
                    u32 hi = f2h(acc[t + 4][j] + bv_l[t]);
                    KV[(size_t)(rbase + j) * 64 + ch] = (hi << 16) | lo;
                }
            }
        }
    }
}

// ---------------- edge attention ----------------
__global__ __launch_bounds__(256) void k_edge(
    const float* __restrict__ QX, const u32* __restrict__ KV, float* __restrict__ X,
    const int* __restrict__ rowptr, const int* __restrict__ colsrc,
    const float4* __restrict__ ea4,
    const float* __restrict__ We, const float* __restrict__ Wbeta)
{
    const float SCL = 0.25f * 1.4426950408889634f;
    int lane = threadIdx.x & 63;
    int node = blockIdx.x * 4 + (threadIdx.x >> 6);
    if (node >= Nn) return;
    float we0 = We[lane], we1 = We[64 + lane];
    float we2 = We[128 + lane], we3 = We[192 + lane];
    float wbA = Wbeta[lane] + Wbeta[128 + lane];
    float wbB = Wbeta[64 + lane] - Wbeta[128 + lane];
    const float* qrow = QX + (size_t)node * 128;
    float q = qrow[lane] * SCL;
    float xr = qrow[64 + lane];
    int jb = rowptr[node], je = rowptr[node + 1];
    float l0 = 0.f, l1 = 0.f, a0 = 0.f, a1 = 0.f;
    int j = jb;
    for (; j + 3 < je; j += 4) {
        int src[4]; float4 eb[4]; u32 kv[4];
#pragma unroll
        for (int c = 0; c < 4; ++c) src[c] = colsrc[j + c];
#pragma unroll
        for (int c = 0; c < 4; ++c) kv[c] = KV[(src[c] << 6) | lane];
#pragma unroll
        for (int c = 0; c < 4; ++c) eb[c] = ea4[j + c];
        float pe[4], ve[4];
#pragma unroll
        for (int c = 0; c < 4; ++c) {
            float e = we0 * eb[c].x;
            e = fmaf(we1, eb[c].y, e); e = fmaf(we2, eb[c].z, e); e = fmaf(we3, eb[c].w, e);
            float ke = h2f_lo(kv[c]) + e;
            ve[c] = h2f_hi(kv[c]) + e;
            float p = red16(q * ke);
            pe[c] = fexp2(p);
        }
        l0 += pe[0]; l1 += pe[1];
        a0 = fmaf(pe[0], ve[0], a0); a1 = fmaf(pe[1], ve[1], a1);
        l0 += pe[2]; l1 += pe[3];
        a0 = fmaf(pe[2], ve[2], a0); a1 = fmaf(pe[3], ve[3], a1);
    }
    for (; j < je; ++j) {
        int s0 = colsrc[j];
        float4 eb0 = ea4[j];
        u32 kv0 = KV[(s0 << 6) | lane];
        float e0 = we0 * eb0.x;
        e0 = fmaf(we1, eb0.y, e0); e0 = fmaf(we2, eb0.z, e0); e0 = fmaf(we3, eb0.w, e0);
        float ke0 = h2f_lo(kv0) + e0, ve0 = h2f_hi(kv0) + e0;
        float p0 = red16(q * ke0);
        float pe0 = fexp2(p0);
        l0 += pe0;
        a0 = fmaf(pe0, ve0, a0);
    }
    float lsum = l0 + l1;
    float acc = a0 + a1;
    float outv = acc / (lsum + 1e-16f);
    float tb = outv * wbA + xr * wbB;
#pragma unroll
    for (int off = 32; off; off >>= 1) tb += __shfl_xor(tb, off);
    float beta = 1.f / (1.f + __expf(-tb));
    float res = beta * xr + (1.f - beta) * outv;
    X[(size_t)node * 64 + lane] += res;
}

// ---------------- LN2 + FFN1 (64->128) + GELU -> G f16 ----------------
__global__ __launch_bounds__(256) void k_ffn1_m(const float* __restrict__ X, u16* __restrict__ G16,
    const float* __restrict__ W1, const float* __restrict__ b1,
    const float* __restrict__ lng, const float* __restrict__ lnb)
{
    const int lane = threadIdx.x & 63;
    const int wid = (blockIdx.x * 256 + threadIdx.x) >> 6;
    const int nw = gridDim.x * 4;
    const int ch_base = lane & 15;
    const int k0b = (lane >> 4) * 8;
    f16x8 bw[8][2];
#pragma unroll
    for (int t = 0; t < 8; ++t)
#pragma unroll
        for (int s = 0; s < 2; ++s)
            bw[t][s] = load_bfrag(W1, 128, t * 16 + ch_base, s * 32 + k0b);
    float b1_l[8];
#pragma unroll
    for (int t = 0; t < 8; ++t) b1_l[t] = b1[t * 16 + ch_base];
    for (int g = wid; g < NG; g += nw) {
        int n0 = g * 16;
        f16x8 a[2];
        build_ln_a(X, n0, lane, lng, lnb, a);
        f32x4 acc[8];
#pragma unroll
        for (int t = 0; t < 8; ++t) { acc[t][0] = 0.f; acc[t][1] = 0.f; acc[t][2] = 0.f; acc[t][3] = 0.f; }
#pragma unroll
        for (int t = 0; t < 8; ++t)
#pragma unroll
            for (int s = 0; s < 2; ++s)
                acc[t] = __builtin_amdgcn_mfma_f32_16x16x32_f16(a[s], bw[t][s], acc[t], 0, 0, 0);
        int rbase = n0 + (lane >> 4) * 4;
#pragma unroll
        for (int t = 0; t < 8; ++t) {
            int ch = t * 16 + ch_base;
#pragma unroll
            for (int j = 0; j < 4; ++j) {
                float v = acc[t][j] + b1_l[t];
                float o = 0.5f * v * (1.f + erff(v * 0.7071067811865476f));
                G16[(size_t)(rbase + j) * 128 + ch] = f2h(o);
            }
        }
    }
}

// ---------------- FFN2 (128->64) + residual into X (+ fused pool on last layer) ----------------
__global__ __launch_bounds__(256) void k_ffn2_m(const u16* __restrict__ G16, float* __restrict__ X,
    const float* __restrict__ W2, const float* __restrict__ b2,
    const int* __restrict__ batch, u32* __restrict__ pkeys, int dopool)
{
    const int lane = threadIdx.x & 63;
    const int wid = (blockIdx.x * 256 + threadIdx.x) >> 6;
    const int nw = gridDim.x * 4;
    const int ch_base = lane & 15;
    const int k0b = (lane >> 4) * 8;
    f16x8 bw[4][4];
#pragma unroll
    for (int t = 0; t < 4; ++t)
#pragma unroll
        for (int s = 0; s < 4; ++s)
            bw[t][s] = load_bfrag(W2, 64, t * 16 + ch_base, s * 32 + k0b);
    float b2_l[4];
#pragma unroll
    for (int t = 0; t < 4; ++t) b2_l[t] = b2[t * 16 + ch_base];
    for (int g = wid; g < NG; g += nw) {
        int n0 = g * 16;
        const u16* gp = G16 + (size_t)(n0 + ch_base) * 128 + k0b;
        f16x8 a0 = *(const f16x8*)(gp);
        f16x8 a1 = *(const f16x8*)(gp + 32);
        f16x8 a2 = *(const f16x8*)(gp + 64);
        f16x8 a3 = *(const f16x8*)(gp + 96);
        f32x4 acc[4];
#pragma unroll
        for (int t = 0; t < 4; ++t) { acc[t][0] = 0.f; acc[t][1] = 0.f; acc[t][2] = 0.f; acc[t][3] = 0.f; }
#pragma unroll
        for (int t = 0; t < 4; ++t) {
            acc[t] = __builtin_amdgcn_mfma_f32_16x16x32_f16(a0, bw[t][0], acc[t], 0, 0, 0);
            acc[t] = __builtin_amdgcn_mfma_f32_16x16x32_f16(a1, bw[t][1], acc[t], 0, 0, 0);
            acc[t] = __builtin_amdgcn_mfma_f32_16x16x32_f16(a2, bw[t][2], acc[t], 0, 0, 0);
            acc[t] = __builtin_amdgcn_mfma_f32_16x16x32_f16(a3, bw[t][3], acc[t], 0, 0, 0);
        }
        int rbase = n0 + (lane >> 4) * 4;
#pragma unroll
        for (int t = 0; t < 4; ++t) {
            int ch = t * 16 + ch_base;
#pragma unroll
            for (int j = 0; j < 4; ++j) {
                int n = rbase + j;
                float* dst = X + (size_t)n * 64 + ch;
                float v = *dst + acc[t][j] + b2_l[t];
                *dst = v;
                if (dopool) {
                    u32 u = __float_as_uint(v);
                    u32 key = (u >> 31) ? ~u : (u | 0x80000000u);
                    atomicMax(&pkeys[batch[n] * 64 + ch], key);
                }
            }
        }
    }
}

// ---------------- head ----------------
__global__ __launch_bounds__(128) void k_head(const u32* __restrict__ pkeys,
    const float* __restrict__ Wo1, const float* __restrict__ bo1,
    const float* __restrict__ Wo2, const float* __restrict__ bo2,
    float* __restrict__ out)
{
    __shared__ float P[64];
    __shared__ float E1[128];
    __shared__ float wred[2];
    int b = blockIdx.x, t = threadIdx.x;
    if (t < 64) {
        u32 k = pkeys[b * 64 + t];
        float v = 0.f;
        if (k) v = (k >> 31) ? __uint_as_float(k ^ 0x80000000u) : __uint_as_float(~k);
        P[t] = v;
    }
    __syncthreads();
    float a = bo1[t];
#pragma unroll 8
    for (int k = 0; k < 64; ++k) a = fmaf(P[k], Wo1[k * 128 + t], a);
    E1[t] = fmaxf(a, 0.f);
    __syncthreads();
    float o = bo2[t];
#pragma unroll 8
    for (int k = 0; k < 128; ++k) o = fmaf(E1[k], Wo2[k * 128 + t], o);
    float ss = o * o;
#pragma unroll
    for (int off = 32; off; off >>= 1) ss += __shfl_xor(ss, off);
    if ((t & 63) == 0) wred[t >> 6] = ss;
    __syncthreads();
    float tot = wred[0] + wred[1];
    float nrm = fmaxf(sqrtf(tot), 1e-12f);
    out[b * 128 + t] = o / nrm;
}

// ---------------- launch ----------------
extern "C" void kernel_launch(void* const* d_in, const int* in_sizes, int n_in,
                              void* d_out, int out_size, void* d_ws, size_t ws_size,
                              hipStream_t stream)
{
    const float* x         = (const float*)d_in[0];
    const float* edge_attr = (const float*)d_in[1];
    const int* ei          = (const int*)d_in[2];
    const int* batch       = (const int*)d_in[3];
    const float* Win  = (const float*)d_in[4];
    const float* bin  = (const float*)d_in[5];
    const float* ln1g = (const float*)d_in[6];
    const float* ln1b = (const float*)d_in[7];
    const float* Wq   = (const float*)d_in[8];
    const float* bq   = (const float*)d_in[9];
    const float* Wk   = (const float*)d_in[10];
    const float* bk   = (const float*)d_in[11];
    const float* Wv   = (const float*)d_in[12];
    const float* bv   = (const float*)d_in[13];
    const float* We   = (const float*)d_in[14];
    const float* Wsk  = (const float*)d_in[15];
    const float* bsk  = (const float*)d_in[16];
    const float* Wbe  = (const float*)d_in[17];
    const float* ln2g = (const float*)d_in[18];
    const float* ln2b = (const float*)d_in[19];
    const float* W1   = (const float*)d_in[20];
    const float* b1   = (const float*)d_in[21];
    const float* W2   = (const float*)d_in[22];
    const float* b2   = (const float*)d_in[23];
    const float* Wo1  = (const float*)d_in[24];
    const float* bo1  = (const float*)d_in[25];
    const float* Wo2  = (const float*)d_in[26];
    const float* bo2  = (const float*)d_in[27];

    char* wsp = (char*)d_ws;
    size_t off = 0;
    auto alloc = [&](size_t bytes) { void* p = wsp + off; off = (off + bytes + 255) & ~(size_t)255; return p; };
    float*   X      = (float*)alloc((size_t)Nn * 64 * 4);
    float*   QX     = (float*)alloc((size_t)Nn * 128 * 4);
    u32*     KV     = (u32*)alloc((size_t)Nn * 64 * 4);
    u16*     G16    = (u16*)alloc((size_t)Nn * 128 * 2);
    int*     rowptr = (int*)alloc((size_t)(Nn + 1) * 4);
    int*     deg    = (int*)alloc((size_t)Nn * 4);
    int*     cursor = (int*)alloc((size_t)Nn * 4);
    int*     psum   = (int*)alloc((size_t)SCB * 4);
    int*     poff   = (int*)alloc((size_t)SCB * 4);
    int*     colsrc = (int*)alloc((size_t)Ee * 4);
    float4*  ea4    = (float4*)alloc((size_t)Ee * 16);
    u32*     pkeys  = (u32*)alloc((size_t)Bb * 64 * 4);

    hipMemsetAsync(deg, 0, (size_t)Nn * 4, stream);
    hipMemsetAsync(cursor, 0, (size_t)Nn * 4, stream);
    hipMemsetAsync(pkeys, 0, (size_t)Bb * 64 * 4, stream);

    k_input_proj<<<12500, 256, 0, stream>>>(x, Win, bin, X);
    k_hist<<<(Ee + 255) / 256, 256, 0, stream>>>(ei, deg);
    k_part<<<SCB, 256, 0, stream>>>(deg, psum);
    k_scanp<<<1, 256, 0, stream>>>(psum, poff);
    k_apply<<<SCB, 256, 0, stream>>>(deg, poff, rowptr);
    k_scatter<<<(Ee + 255) / 256, 256, 0, stream>>>(ei, edge_attr, rowptr, cursor, colsrc, ea4);

    for (int l = 0; l < 3; ++l) {
        k_proj<<<GB, 256, 0, stream>>>(X, QX, KV,
            Wq + l * 4096, Wsk + l * 4096, Wk + l * 4096, Wv + l * 4096,
            bq + l * 64, bsk + l * 64, bk + l * 64, bv + l * 64,
            ln1g + l * 64, ln1b + l * 64);
        k_edge<<<Nn / 4, 256, 0, stream>>>(QX, KV, X, rowptr, colsrc, ea4,
            We + l * 256, Wbe + l * 192);
        k_ffn1_m<<<GB, 256, 0, stream>>>(X, G16, W1 + l * 8192, b1 + l * 128,
            ln2g + l * 64, ln2b + l * 64);
        k_ffn2_m<<<GB, 256, 0, stream>>>(G16, X, W2 + l * 8192, b2 + l * 64,
            batch, pkeys, (l == 2) ? 1 : 0);
    }
    k_head<<<Bb, 128, 0, stream>>>(pkeys, Wo1, bo1, Wo2, bo2, (float*)d_out);
}

// Round 10
// 449.607 us; speedup vs baseline: 1.1242x; 1.0727x over previous
//
#include <hip/hip_runtime.h>
#include <hip/hip_bf16.h>
#include <hip/hip_fp16.h>

#define Nn 50000
#define Ee 1000000
#define Bb 512
#define NG 3125   // 50000/16 node-row groups (exact)
#define SCB 196   // ceil(50000/256) scan blocks
#define GB 782    // dense-kernel grid: 782*4=3128 waves >= 3125 groups (1 group/wave)

typedef unsigned short u16;
typedef unsigned int u32;
typedef _Float16 f16;
typedef _Float16 f16x2 __attribute__((ext_vector_type(2)));
typedef _Float16 f16x8 __attribute__((ext_vector_type(8)));
typedef float f32x4 __attribute__((ext_vector_type(4)));

__device__ __forceinline__ u16 f2h(float f) { return __half_as_ushort(__float2half(f)); }
__device__ __forceinline__ float h2f_lo(u32 kv) { return __half2float(__ushort_as_half((u16)(kv & 0xffff))); }
__device__ __forceinline__ float h2f_hi(u32 kv) { return __half2float(__ushort_as_half((u16)(kv >> 16))); }
__device__ __forceinline__ f16x2 as_h2(u32 v) { union { u32 u; f16x2 h; } c; c.u = v; return c.h; }

__device__ __forceinline__ float fexp2(float x) {
    float r;
    asm("v_exp_f32 %0, %1" : "=v"(r) : "v"(x));
    return r;
}

// butterfly sum over each 16-lane group (one head) via DPP
__device__ __forceinline__ float red16(float x) {
    int t;
    t = __builtin_amdgcn_update_dpp(0, __float_as_int(x), 0xB1, 0xF, 0xF, true);   // quad_perm [1,0,3,2]
    x += __int_as_float(t);
    t = __builtin_amdgcn_update_dpp(0, __float_as_int(x), 0x4E, 0xF, 0xF, true);   // quad_perm [2,3,0,1]
    x += __int_as_float(t);
    t = __builtin_amdgcn_update_dpp(0, __float_as_int(x), 0x141, 0xF, 0xF, true);  // row_half_mirror
    x += __int_as_float(t);
    t = __builtin_amdgcn_update_dpp(0, __float_as_int(x), 0x140, 0xF, 0xF, true);  // row_mirror
    x += __int_as_float(t);
    return x;
}

// ---------------- input projection ----------------
__global__ __launch_bounds__(256) void k_input_proj(const float* __restrict__ x,
    const float* __restrict__ Win, const float* __restrict__ bin, float* __restrict__ X)
{
    __shared__ float W[8][64];
    __shared__ float bsh[64];
    int t = threadIdx.x;
    if (t < 64) bsh[t] = bin[t];
    for (int i = t; i < 512; i += 256) W[i >> 6][i & 63] = Win[i];
    __syncthreads();
    int gid = blockIdx.x * 256 + t;
    int n = gid >> 6, c = gid & 63;
    const float* xr = x + n * 8;
    float acc = bsh[c];
#pragma unroll
    for (int k = 0; k < 8; ++k) acc = fmaf(xr[k], W[k][c], acc);
    X[gid] = acc;
}

// ---------------- CSR build ----------------
__global__ __launch_bounds__(256) void k_hist(const int* __restrict__ ei, int* __restrict__ deg)
{
    int e = blockIdx.x * 256 + threadIdx.x;
    if (e < Ee) atomicAdd(&deg[ei[Ee + e]], 1);
}

__global__ __launch_bounds__(256) void k_part(const int* __restrict__ deg, int* __restrict__ psum)
{
    __shared__ int ws[4];
    int b = blockIdx.x, t = threadIdx.x;
    int idx = b * 256 + t;
    int v = (idx < Nn) ? deg[idx] : 0;
    int r = v;
#pragma unroll
    for (int off = 32; off; off >>= 1) r += __shfl_xor(r, off);
    if ((t & 63) == 0) ws[t >> 6] = r;
    __syncthreads();
    if (t == 0) psum[b] = ws[0] + ws[1] + ws[2] + ws[3];
}

__global__ __launch_bounds__(256) void k_scanp(const int* __restrict__ psum, int* __restrict__ poff)
{
    __shared__ int ws[4];
    int t = threadIdx.x, lane = t & 63, w = t >> 6;
    int v = (t < SCB) ? psum[t] : 0;
    int s = v;
#pragma unroll
    for (int off = 1; off < 64; off <<= 1) {
        int u = __shfl_up(s, off);
        if (lane >= off) s += u;
    }
    if (lane == 63) ws[w] = s;
    __syncthreads();
    if (t == 0) { int a = 0; for (int i = 0; i < 4; ++i) { a += ws[i]; ws[i] = a; } }
    __syncthreads();
    int incl = s + (w ? ws[w - 1] : 0);
    if (t < SCB) poff[t] = incl - v;
}

__global__ __launch_bounds__(256) void k_apply(const int* __restrict__ deg, const int* __restrict__ poff,
    int* __restrict__ rowptr)
{
    __shared__ int ws[4];
    int b = blockIdx.x, t = threadIdx.x, lane = t & 63, w = t >> 6;
    int idx = b * 256 + t;
    int v = (idx < Nn) ? deg[idx] : 0;
    int s = v;
#pragma unroll
    for (int off = 1; off < 64; off <<= 1) {
        int u = __shfl_up(s, off);
        if (lane >= off) s += u;
    }
    if (lane == 63) ws[w] = s;
    __syncthreads();
    if (t == 0) { int a = 0; for (int i = 0; i < 4; ++i) { a += ws[i]; ws[i] = a; } }
    __syncthreads();
    int incl = s + (w ? ws[w - 1] : 0) + poff[b];
    if (idx < Nn) rowptr[idx + 1] = incl;
    if (b == 0 && t == 0) rowptr[0] = 0;
}

// scatter one packed 16B record per edge: {src, (a1|a0) f16, (a3|a2) f16, 0}
__global__ __launch_bounds__(256) void k_scatter(const int* __restrict__ ei, const float* __restrict__ eattr,
    const int* __restrict__ rowptr, int* __restrict__ cursor, int4* __restrict__ EC)
{
    int e = blockIdx.x * 256 + threadIdx.x;
    if (e >= Ee) return;
    int d = ei[Ee + e];
    int pos = rowptr[d] + atomicAdd(&cursor[d], 1);
    float4 ea = *(const float4*)(eattr + (size_t)e * 4);
    int4 rec;
    rec.x = ei[e];
    rec.y = (int)(((u32)f2h(ea.y) << 16) | f2h(ea.x));
    rec.z = (int)(((u32)f2h(ea.w) << 16) | f2h(ea.z));
    rec.w = 0;
    EC[pos] = rec;
}

// ---------------- MFMA helpers ----------------
__device__ __forceinline__ f16x8 load_bfrag(const float* __restrict__ W, int NC, int col, int k0)
{
    f16x8 b;
    const float* wp = W + (size_t)k0 * NC + col;
#pragma unroll
    for (int i = 0; i < 8; ++i) b[i] = (f16)wp[i * NC];
    return b;
}

__device__ __forceinline__ void build_ln_a(const float* __restrict__ X, int n0, int lane,
    const float* __restrict__ lng, const float* __restrict__ lnb, f16x8* a)
{
    const int r = lane & 15, c = lane >> 4;
    const float* xp = X + (size_t)(n0 + r) * 64 + c * 8;
    float4 x0 = *(const float4*)(xp);
    float4 x1 = *(const float4*)(xp + 4);
    float4 x2 = *(const float4*)(xp + 32);
    float4 x3 = *(const float4*)(xp + 36);
    float xs[16] = {x0.x, x0.y, x0.z, x0.w, x1.x, x1.y, x1.z, x1.w,
                    x2.x, x2.y, x2.z, x2.w, x3.x, x3.y, x3.z, x3.w};
    float s = 0.f, s2 = 0.f;
#pragma unroll
    for (int i = 0; i < 16; ++i) { s += xs[i]; s2 = fmaf(xs[i], xs[i], s2); }
    s += __shfl_xor(s, 16);  s += __shfl_xor(s, 32);
    s2 += __shfl_xor(s2, 16); s2 += __shfl_xor(s2, 32);
    float mu = s * 0.015625f;
    float var = s2 * 0.015625f - mu * mu;
    float rstd = rsqrtf(fmaxf(var, 0.f) + 1e-5f);
    const float* gp = lng + c * 8;
    const float* bp = lnb + c * 8;
    float4 g0 = *(const float4*)(gp),      g1 = *(const float4*)(gp + 4);
    float4 g2 = *(const float4*)(gp + 32), g3 = *(const float4*)(gp + 36);
    float4 b0 = *(const float4*)(bp),      b1 = *(const float4*)(bp + 4);
    float4 b2 = *(const float4*)(bp + 32), b3 = *(const float4*)(bp + 36);
    float gs[16] = {g0.x, g0.y, g0.z, g0.w, g1.x, g1.y, g1.z, g1.w,
                    g2.x, g2.y, g2.z, g2.w, g3.x, g3.y, g3.z, g3.w};
    float bs[16] = {b0.x, b0.y, b0.z, b0.w, b1.x, b1.y, b1.z, b1.w,
                    b2.x, b2.y, b2.z, b2.w, b3.x, b3.y, b3.z, b3.w};
#pragma unroll
    for (int i = 0; i < 16; ++i) {
        float h = (xs[i] - mu) * rstd * gs[i] + bs[i];
        a[i >> 3][i & 7] = (f16)h;
    }
}

// ---------------- fused LN1 + Q,Skip + K,V projections (two weight phases) ----------------
__global__ __launch_bounds__(256) void k_proj(const float* __restrict__ X,
    float* __restrict__ QX, u32* __restrict__ KV,
    const float* __restrict__ Wq, const float* __restrict__ Ws,
    const float* __restrict__ Wk, const float* __restrict__ Wv,
    const float* __restrict__ bq, const float* __restrict__ bs_,
    const float* __restrict__ bk, const float* __restrict__ bv,
    const float* __restrict__ lng, const float* __restrict__ lnb)
{
    const int lane = threadIdx.x & 63;
    const int wid = (blockIdx.x * 256 + threadIdx.x) >> 6;
    const int nw = gridDim.x * 4;
    const int ch_base = lane & 15;
    const int k0b = (lane >> 4) * 8;
    float bq_l[4], bs_l[4], bk_l[4], bv_l[4];
#pragma unroll
    for (int t = 0; t < 4; ++t) {
        bq_l[t] = bq[t * 16 + ch_base]; bs_l[t] = bs_[t * 16 + ch_base];
        bk_l[t] = bk[t * 16 + ch_base]; bv_l[t] = bv[t * 16 + ch_base];
    }
    for (int g = wid; g < NG; g += nw) {
        int n0 = g * 16;
        f16x8 a[2];
        build_ln_a(X, n0, lane, lng, lnb, a);
        int rbase = n0 + (lane >> 4) * 4;
        // phase 1: Q | Skip -> QX
        {
            f16x8 bw[8][2];
#pragma unroll
            for (int t = 0; t < 4; ++t)
#pragma unroll
                for (int s = 0; s < 2; ++s) {
                    bw[t][s]     = load_bfrag(Wq, 64, t * 16 + ch_base, s * 32 + k0b);
                    bw[t + 4][s] = load_bfrag(Ws, 64, t * 16 + ch_base, s * 32 + k0b);
                }
            f32x4 acc[8];
#pragma unroll
            for (int t = 0; t < 8; ++t) { acc[t][0] = 0.f; acc[t][1] = 0.f; acc[t][2] = 0.f; acc[t][3] = 0.f; }
#pragma unroll
            for (int t = 0; t < 8; ++t)
#pragma unroll
                for (int s = 0; s < 2; ++s)
                    acc[t] = __builtin_amdgcn_mfma_f32_16x16x32_f16(a[s], bw[t][s], acc[t], 0, 0, 0);
#pragma unroll
            for (int t = 0; t < 4; ++t) {
                int ch = t * 16 + ch_base;
#pragma unroll
                for (int j = 0; j < 4; ++j) {
                    float* dst = QX + (size_t)(rbase + j) * 128;
                    dst[ch] = acc[t][j] + bq_l[t];
                    dst[64 + ch] = acc[t + 4][j] + bs_l[t];
                }
            }
        }
        // phase 2: K | V -> packed f16 KV
        {
            f16x8 bw[8][2];
#pragma unroll
            for (int t = 0; t < 4; ++t)
#pragma unroll
                for (int s = 0; s < 2; ++s) {
                    bw[t][s]     = load_bfrag(Wk, 64, t * 16 + ch_base, s * 32 + k0b);
                    bw[t + 4][s] = load_bfrag(Wv, 64, t * 16 + ch_base, s * 32 + k0b);
                }
            f32x4 acc[8];
#pragma unroll
            for (int t = 0; t < 8; ++t) { acc[t][0] = 0.f; acc[t][1] = 0.f; acc[t][2] = 0.f; acc[t][3] = 0.f; }
#pragma unroll
            for (int t = 0; t < 8; ++t)
#pragma unroll
                for (int s = 0; s < 2; ++s)
                    acc[t] = __builtin_amdgcn_mfma_f32_16x16x32_f16(a[s], bw[t][s], acc[t], 0, 0, 0);
#pragma unroll
            for (int t = 0; t < 4; ++t) {
                int ch = t * 16 + ch_base;
#pragma unroll
                for (int j = 0; j < 4; ++j) {
                    u32 lo = f2h(acc[t][j] + bk_l[t]);
                    u32 hi = f2h(acc[t + 4][j] + bv_l[t]);
                    KV[(size_t)(rbase + j) * 64 + ch] = (hi << 16) | lo;
                }
            }
        }
    }
}

// ---------------- edge attention: scalarized uniform loads + fdot2 + DPP reduce ----------------
__global__ __launch_bounds__(256) void k_edge(
    const float* __restrict__ QX, const u32* __restrict__ KV, float* __restrict__ X,
    const int* __restrict__ rowptr, const int4* __restrict__ EC,
    const float* __restrict__ We, const float* __restrict__ Wbeta)
{
    const float SCL = 0.25f * 1.4426950408889634f;
    int lane = threadIdx.x & 63;
    // grid is exact: 12500 blocks * 4 waves = 50000 nodes
    int node = __builtin_amdgcn_readfirstlane(blockIdx.x * 4 + (threadIdx.x >> 6));
    f16x2 w01, w23;
    w01[0] = (f16)We[lane];        w01[1] = (f16)We[64 + lane];
    w23[0] = (f16)We[128 + lane];  w23[1] = (f16)We[192 + lane];
    float wbA = Wbeta[lane] + Wbeta[128 + lane];
    float wbB = Wbeta[64 + lane] - Wbeta[128 + lane];
    const float* qrow = QX + (size_t)node * 128;
    float q = qrow[lane] * SCL;
    float xr = qrow[64 + lane];
    int jb = rowptr[node], je = rowptr[node + 1];
    float l0 = 0.f, l1 = 0.f, a0 = 0.f, a1 = 0.f;
    int j = jb;
    for (; j + 3 < je; j += 4) {
        int4 r0 = EC[j], r1 = EC[j + 1], r2 = EC[j + 2], r3 = EC[j + 3];
        u32 kv0 = KV[(r0.x << 6) | lane];
        u32 kv1 = KV[(r1.x << 6) | lane];
        u32 kv2 = KV[(r2.x << 6) | lane];
        u32 kv3 = KV[(r3.x << 6) | lane];
        float e0 = __builtin_amdgcn_fdot2(w01, as_h2((u32)r0.y),
                     __builtin_amdgcn_fdot2(w23, as_h2((u32)r0.z), 0.f, false), false);
        float e1 = __builtin_amdgcn_fdot2(w01, as_h2((u32)r1.y),
                     __builtin_amdgcn_fdot2(w23, as_h2((u32)r1.z), 0.f, false), false);
        float e2 = __builtin_amdgcn_fdot2(w01, as_h2((u32)r2.y),
                     __builtin_amdgcn_fdot2(w23, as_h2((u32)r2.z), 0.f, false), false);
        float e3 = __builtin_amdgcn_fdot2(w01, as_h2((u32)r3.y),
                     __builtin_amdgcn_fdot2(w23, as_h2((u32)r3.z), 0.f, false), false);
        float ke0 = h2f_lo(kv0) + e0, ve0 = h2f_hi(kv0) + e0;
        float ke1 = h2f_lo(kv1) + e1, ve1 = h2f_hi(kv1) + e1;
        float ke2 = h2f_lo(kv2) + e2, ve2 = h2f_hi(kv2) + e2;
        float ke3 = h2f_lo(kv3) + e3, ve3 = h2f_hi(kv3) + e3;
        float pe0 = fexp2(red16(q * ke0));
        float pe1 = fexp2(red16(q * ke1));
        float pe2 = fexp2(red16(q * ke2));
        float pe3 = fexp2(red16(q * ke3));
        l0 += pe0; a0 = fmaf(pe0, ve0, a0);
        l1 += pe1; a1 = fmaf(pe1, ve1, a1);
        l0 += pe2; a0 = fmaf(pe2, ve2, a0);
        l1 += pe3; a1 = fmaf(pe3, ve3, a1);
    }
    for (; j < je; ++j) {
        int4 r0 = EC[j];
        u32 kv0 = KV[(r0.x << 6) | lane];
        float e0 = __builtin_amdgcn_fdot2(w01, as_h2((u32)r0.y),
                     __builtin_amdgcn_fdot2(w23, as_h2((u32)r0.z), 0.f, false), false);
        float ke0 = h2f_lo(kv0) + e0, ve0 = h2f_hi(kv0) + e0;
        float pe0 = fexp2(red16(q * ke0));
        l0 += pe0;
        a0 = fmaf(pe0, ve0, a0);
    }
    float lsum = l0 + l1;
    float acc = a0 + a1;
    float outv = acc / (lsum + 1e-16f);
    float tb = outv * wbA + xr * wbB;
#pragma unroll
    for (int off = 32; off; off >>= 1) tb += __shfl_xor(tb, off);
    float beta = 1.f / (1.f + __expf(-tb));
    float res = beta * xr + (1.f - beta) * outv;
    X[(size_t)node * 64 + lane] += res;
}

// ---------------- LN2 + FFN1 (64->128) + GELU -> G f16 ----------------
__global__ __launch_bounds__(256) void k_ffn1_m(const float* __restrict__ X, u16* __restrict__ G16,
    const float* __restrict__ W1, const float* __restrict__ b1,
    const float* __restrict__ lng, const float* __restrict__ lnb)
{
    const int lane = threadIdx.x & 63;
    const int wid = (blockIdx.x * 256 + threadIdx.x) >> 6;
    const int nw = gridDim.x * 4;
    const int ch_base = lane & 15;
    const int k0b = (lane >> 4) * 8;
    f16x8 bw[8][2];
#pragma unroll
    for (int t = 0; t < 8; ++t)
#pragma unroll
        for (int s = 0; s < 2; ++s)
            bw[t][s] = load_bfrag(W1, 128, t * 16 + ch_base, s * 32 + k0b);
    float b1_l[8];
#pragma unroll
    for (int t = 0; t < 8; ++t) b1_l[t] = b1[t * 16 + ch_base];
    for (int g = wid; g < NG; g += nw) {
        int n0 = g * 16;
        f16x8 a[2];
        build_ln_a(X, n0, lane, lng, lnb, a);
        f32x4 acc[8];
#pragma unroll
        for (int t = 0; t < 8; ++t) { acc[t][0] = 0.f; acc[t][1] = 0.f; acc[t][2] = 0.f; acc[t][3] = 0.f; }
#pragma unroll
        for (int t = 0; t < 8; ++t)
#pragma unroll
            for (int s = 0; s < 2; ++s)
                acc[t] = __builtin_amdgcn_mfma_f32_16x16x32_f16(a[s], bw[t][s], acc[t], 0, 0, 0);
        int rbase = n0 + (lane >> 4) * 4;
#pragma unroll
        for (int t = 0; t < 8; ++t) {
            int ch = t * 16 + ch_base;
#pragma unroll
            for (int j = 0; j < 4; ++j) {
                float v = acc[t][j] + b1_l[t];
                float o = 0.5f * v * (1.f + erff(v * 0.7071067811865476f));
                G16[(size_t)(rbase + j) * 128 + ch] = f2h(o);
            }
        }
    }
}

// ---------------- FFN2 (128->64) + residual into X (+ fused pool on last layer) ----------------
__global__ __launch_bounds__(256) void k_ffn2_m(const u16* __restrict__ G16, float* __restrict__ X,
    const float* __restrict__ W2, const float* __restrict__ b2,
    const int* __restrict__ batch, u32* __restrict__ pkeys, int dopool)
{
    const int lane = threadIdx.x & 63;
    const int wid = (blockIdx.x * 256 + threadIdx.x) >> 6;
    const int nw = gridDim.x * 4;
    const int ch_base = lane & 15;
    const int k0b = (lane >> 4) * 8;
    f16x8 bw[4][4];
#pragma unroll
    for (int t = 0; t < 4; ++t)
#pragma unroll
        for (int s = 0; s < 4; ++s)
            bw[t][s] = load_bfrag(W2, 64, t * 16 + ch_base, s * 32 + k0b);
    float b2_l[4];
#pragma unroll
    for (int t = 0; t < 4; ++t) b2_l[t] = b2[t * 16 + ch_base];
    for (int g = wid; g < NG; g += nw) {
        int n0 = g * 16;
        const u16* gp = G16 + (size_t)(n0 + ch_base) * 128 + k0b;
        f16x8 a0 = *(const f16x8*)(gp);
        f16x8 a1 = *(const f16x8*)(gp + 32);
        f16x8 a2 = *(const f16x8*)(gp + 64);
        f16x8 a3 = *(const f16x8*)(gp + 96);
        f32x4 acc[4];
#pragma unroll
        for (int t = 0; t < 4; ++t) { acc[t][0] = 0.f; acc[t][1] = 0.f; acc[t][2] = 0.f; acc[t][3] = 0.f; }
#pragma unroll
        for (int t = 0; t < 4; ++t) {
            acc[t] = __builtin_amdgcn_mfma_f32_16x16x32_f16(a0, bw[t][0], acc[t], 0, 0, 0);
            acc[t] = __builtin_amdgcn_mfma_f32_16x16x32_f16(a1, bw[t][1], acc[t], 0, 0, 0);
            acc[t] = __builtin_amdgcn_mfma_f32_16x16x32_f16(a2, bw[t][2], acc[t], 0, 0, 0);
            acc[t] = __builtin_amdgcn_mfma_f32_16x16x32_f16(a3, bw[t][3], acc[t], 0, 0, 0);
        }
        int rbase = n0 + (lane >> 4) * 4;
#pragma unroll
        for (int t = 0; t < 4; ++t) {
            int ch = t * 16 + ch_base;
#pragma unroll
            for (int j = 0; j < 4; ++j) {
                int n = rbase + j;
                float* dst = X + (size_t)n * 64 + ch;
                float v = *dst + acc[t][j] + b2_l[t];
                *dst = v;
                if (dopool) {
                    u32 u = __float_as_uint(v);
                    u32 key = (u >> 31) ? ~u : (u | 0x80000000u);
                    atomicMax(&pkeys[batch[n] * 64 + ch], key);
                }
            }
        }
    }
}

// ---------------- head ----------------
__global__ __launch_bounds__(128) void k_head(const u32* __restrict__ pkeys,
    const float* __restrict__ Wo1, const float* __restrict__ bo1,
    const float* __restrict__ Wo2, const float* __restrict__ bo2,
    float* __restrict__ out)
{
    __shared__ float P[64];
    __shared__ float E1[128];
    __shared__ float wred[2];
    int b = blockIdx.x, t = threadIdx.x;
    if (t < 64) {
        u32 k = pkeys[b * 64 + t];
        float v = 0.f;
        if (k) v = (k >> 31) ? __uint_as_float(k ^ 0x80000000u) : __uint_as_float(~k);
        P[t] = v;
    }
    __syncthreads();
    float a = bo1[t];
#pragma unroll 8
    for (int k = 0; k < 64; ++k) a = fmaf(P[k], Wo1[k * 128 + t], a);
    E1[t] = fmaxf(a, 0.f);
    __syncthreads();
    float o = bo2[t];
#pragma unroll 8
    for (int k = 0; k < 128; ++k) o = fmaf(E1[k], Wo2[k * 128 + t], o);
    float ss = o * o;
#pragma unroll
    for (int off = 32; off; off >>= 1) ss += __shfl_xor(ss, off);
    if ((t & 63) == 0) wred[t >> 6] = ss;
    __syncthreads();
    float tot = wred[0] + wred[1];
    float nrm = fmaxf(sqrtf(tot), 1e-12f);
    out[b * 128 + t] = o / nrm;
}

// ---------------- launch ----------------
extern "C" void kernel_launch(void* const* d_in, const int* in_sizes, int n_in,
                              void* d_out, int out_size, void* d_ws, size_t ws_size,
                              hipStream_t stream)
{
    const float* x         = (const float*)d_in[0];
    const float* edge_attr = (const float*)d_in[1];
    const int* ei          = (const int*)d_in[2];
    const int* batch       = (const int*)d_in[3];
    const float* Win  = (const float*)d_in[4];
    const float* bin  = (const float*)d_in[5];
    const float* ln1g = (const float*)d_in[6];
    const float* ln1b = (const float*)d_in[7];
    const float* Wq   = (const float*)d_in[8];
    const float* bq   = (const float*)d_in[9];
    const float* Wk   = (const float*)d_in[10];
    const float* bk   = (const float*)d_in[11];
    const float* Wv   = (const float*)d_in[12];
    const float* bv   = (const float*)d_in[13];
    const float* We   = (const float*)d_in[14];
    const float* Wsk  = (const float*)d_in[15];
    const float* bsk  = (const float*)d_in[16];
    const float* Wbe  = (const float*)d_in[17];
    const float* ln2g = (const float*)d_in[18];
    const float* ln2b = (const float*)d_in[19];
    const float* W1   = (const float*)d_in[20];
    const float* b1   = (const float*)d_in[21];
    const float* W2   = (const float*)d_in[22];
    const float* b2   = (const float*)d_in[23];
    const float* Wo1  = (const float*)d_in[24];
    const float* bo1  = (const float*)d_in[25];
    const float* Wo2  = (const float*)d_in[26];
    const float* bo2  = (const float*)d_in[27];

    char* wsp = (char*)d_ws;
    size_t off = 0;
    auto alloc = [&](size_t bytes) { void* p = wsp + off; off = (off + bytes + 255) & ~(size_t)255; return p; };
    float*   X      = (float*)alloc((size_t)Nn * 64 * 4);
    float*   QX     = (float*)alloc((size_t)Nn * 128 * 4);
    u32*     KV     = (u32*)alloc((size_t)Nn * 64 * 4);
    u16*     G16    = (u16*)alloc((size_t)Nn * 128 * 2);
    int*     rowptr = (int*)alloc((size_t)(Nn + 1) * 4);
    int*     deg    = (int*)alloc((size_t)Nn * 4);
    int*     cursor = (int*)alloc((size_t)Nn * 4);
    int*     psum   = (int*)alloc((size_t)SCB * 4);
    int*     poff   = (int*)alloc((size_t)SCB * 4);
    int4*    EC     = (int4*)alloc((size_t)Ee * 16);
    u32*     pkeys  = (u32*)alloc((size_t)Bb * 64 * 4);

    hipMemsetAsync(deg, 0, (size_t)Nn * 4, stream);
    hipMemsetAsync(cursor, 0, (size_t)Nn * 4, stream);
    hipMemsetAsync(pkeys, 0, (size_t)Bb * 64 * 4, stream);

    k_input_proj<<<12500, 256, 0, stream>>>(x, Win, bin, X);
    k_hist<<<(Ee + 255) / 256, 256, 0, stream>>>(ei, deg);
    k_part<<<SCB, 256, 0, stream>>>(deg, psum);
    k_scanp<<<1, 256, 0, stream>>>(psum, poff);
    k_apply<<<SCB, 256, 0, stream>>>(deg, poff, rowptr);
    k_scatter<<<(Ee + 255) / 256, 256, 0, stream>>>(ei, edge_attr, rowptr, cursor, EC);

    for (int l = 0; l < 3; ++l) {
        k_proj<<<GB, 256, 0, stream>>>(X, QX, KV,
            Wq + l * 4096, Wsk + l * 4096, Wk + l * 4096, Wv + l * 4096,
            bq + l * 64, bsk + l * 64, bk + l * 64, bv + l * 64,
            ln1g + l * 64, ln1b + l * 64);
        k_edge<<<Nn / 4, 256, 0, stream>>>(QX, KV, X, rowptr, EC,
            We + l * 256, Wbe + l * 192);
        k_ffn1_m<<<GB, 256, 0, stream>>>(X, G16, W1 + l * 8192, b1 + l * 128,
            ln2g + l * 64, ln2b + l * 64);
        k_ffn2_m<<<GB, 256, 0, stream>>>(G16, X, W2 + l * 8192, b2 + l * 64,
            batch, pkeys, (l == 2) ? 1 : 0);
    }
    k_head<<<Bb, 128, 0, stream>>>(pkeys, Wo1, bo1, Wo2, bo2, (float*)d_out);
}

// Round 12
// 437.677 us; speedup vs baseline: 1.1548x; 1.0273x over previous
//
#include <hip/hip_runtime.h>
#include <hip/hip_bf16.h>
#include <hip/hip_fp16.h>

#define Nn 50000
#define Ee 1000000
#define Bb 512
#define NG 3125   // 50000/16 node-row groups (exact)
#define SCB 196   // ceil(50000/256) scan blocks
#define GB 782    // dense-kernel grid: 782*4=3128 waves >= 3125 groups (1 group/wave)

typedef unsigned short u16;
typedef unsigned int u32;
typedef _Float16 f16;
typedef _Float16 f16x2 __attribute__((ext_vector_type(2)));
typedef _Float16 f16x8 __attribute__((ext_vector_type(8)));
typedef float f32x4 __attribute__((ext_vector_type(4)));
typedef int i32x4 __attribute__((ext_vector_type(4)));

__device__ __forceinline__ u16 f2h(float f) { return __half_as_ushort(__float2half(f)); }
__device__ __forceinline__ float h2f(u16 h) { return __half2float(__ushort_as_half(h)); }
__device__ __forceinline__ float h2f_lo(u32 kv) { return __half2float(__ushort_as_half((u16)(kv & 0xffff))); }
__device__ __forceinline__ float h2f_hi(u32 kv) { return __half2float(__ushort_as_half((u16)(kv >> 16))); }
__device__ __forceinline__ f16x2 as_h2(u32 v) { union { u32 u; f16x2 h; } c; c.u = v; return c.h; }

__device__ __forceinline__ float fexp2(float x) {
    float r;
    asm("v_exp_f32 %0, %1" : "=v"(r) : "v"(x));
    return r;
}

// butterfly sum over each 16-lane group (one head) via DPP
__device__ __forceinline__ float red16(float x) {
    int t;
    t = __builtin_amdgcn_update_dpp(0, __float_as_int(x), 0xB1, 0xF, 0xF, true);   // quad_perm [1,0,3,2]
    x += __int_as_float(t);
    t = __builtin_amdgcn_update_dpp(0, __float_as_int(x), 0x4E, 0xF, 0xF, true);   // quad_perm [2,3,0,1]
    x += __int_as_float(t);
    t = __builtin_amdgcn_update_dpp(0, __float_as_int(x), 0x141, 0xF, 0xF, true);  // row_half_mirror
    x += __int_as_float(t);
    t = __builtin_amdgcn_update_dpp(0, __float_as_int(x), 0x140, 0xF, 0xF, true);  // row_mirror
    x += __int_as_float(t);
    return x;
}

// ---------------- input projection ----------------
__global__ __launch_bounds__(256) void k_input_proj(const float* __restrict__ x,
    const float* __restrict__ Win, const float* __restrict__ bin, float* __restrict__ X)
{
    __shared__ float W[8][64];
    __shared__ float bsh[64];
    int t = threadIdx.x;
    if (t < 64) bsh[t] = bin[t];
    for (int i = t; i < 512; i += 256) W[i >> 6][i & 63] = Win[i];
    __syncthreads();
    int gid = blockIdx.x * 256 + t;
    int n = gid >> 6, c = gid & 63;
    const float* xr = x + n * 8;
    float acc = bsh[c];
#pragma unroll
    for (int k = 0; k < 8; ++k) acc = fmaf(xr[k], W[k][c], acc);
    X[gid] = acc;
}

// ---------------- CSR build ----------------
__global__ __launch_bounds__(256) void k_hist(const int* __restrict__ ei, int* __restrict__ deg)
{
    int e = blockIdx.x * 256 + threadIdx.x;
    if (e < Ee) atomicAdd(&deg[ei[Ee + e]], 1);
}

__global__ __launch_bounds__(256) void k_part(const int* __restrict__ deg, int* __restrict__ psum)
{
    __shared__ int ws[4];
    int b = blockIdx.x, t = threadIdx.x;
    int idx = b * 256 + t;
    int v = (idx < Nn) ? deg[idx] : 0;
    int r = v;
#pragma unroll
    for (int off = 32; off; off >>= 1) r += __shfl_xor(r, off);
    if ((t & 63) == 0) ws[t >> 6] = r;
    __syncthreads();
    if (t == 0) psum[b] = ws[0] + ws[1] + ws[2] + ws[3];
}

__global__ __launch_bounds__(256) void k_scanp(const int* __restrict__ psum, int* __restrict__ poff)
{
    __shared__ int ws[4];
    int t = threadIdx.x, lane = t & 63, w = t >> 6;
    int v = (t < SCB) ? psum[t] : 0;
    int s = v;
#pragma unroll
    for (int off = 1; off < 64; off <<= 1) {
        int u = __shfl_up(s, off);
        if (lane >= off) s += u;
    }
    if (lane == 63) ws[w] = s;
    __syncthreads();
    if (t == 0) { int a = 0; for (int i = 0; i < 4; ++i) { a += ws[i]; ws[i] = a; } }
    __syncthreads();
    int incl = s + (w ? ws[w - 1] : 0);
    if (t < SCB) poff[t] = incl - v;
}

__global__ __launch_bounds__(256) void k_apply(const int* __restrict__ deg, const int* __restrict__ poff,
    int* __restrict__ rowptr)
{
    __shared__ int ws[4];
    int b = blockIdx.x, t = threadIdx.x, lane = t & 63, w = t >> 6;
    int idx = b * 256 + t;
    int v = (idx < Nn) ? deg[idx] : 0;
    int s = v;
#pragma unroll
    for (int off = 1; off < 64; off <<= 1) {
        int u = __shfl_up(s, off);
        if (lane >= off) s += u;
    }
    if (lane == 63) ws[w] = s;
    __syncthreads();
    if (t == 0) { int a = 0; for (int i = 0; i < 4; ++i) { a += ws[i]; ws[i] = a; } }
    __syncthreads();
    int incl = s + (w ? ws[w - 1] : 0) + poff[b];
    if (idx < Nn) rowptr[idx + 1] = incl;
    if (b == 0 && t == 0) rowptr[0] = 0;
}

// scatter one packed 16B record per edge: {src, (a1|a0) f16, (a3|a2) f16, 0}; nontemporal store
__global__ __launch_bounds__(256) void k_scatter(const int* __restrict__ ei, const float* __restrict__ eattr,
    const int* __restrict__ rowptr, int* __restrict__ cursor, i32x4* __restrict__ EC)
{
    int e = blockIdx.x * 256 + threadIdx.x;
    if (e >= Ee) return;
    int d = ei[Ee + e];
    int pos = rowptr[d] + atomicAdd(&cursor[d], 1);
    float4 ea = *(const float4*)(eattr + (size_t)e * 4);
    i32x4 rec;
    rec[0] = ei[e];
    rec[1] = (int)(((u32)f2h(ea.y) << 16) | f2h(ea.x));
    rec[2] = (int)(((u32)f2h(ea.w) << 16) | f2h(ea.z));
    rec[3] = 0;
    __builtin_nontemporal_store(rec, EC + pos);
}

// ---------------- MFMA helpers ----------------
__device__ __forceinline__ f16x8 load_bfrag(const float* __restrict__ W, int NC, int col, int k0)
{
    f16x8 b;
    const float* wp = W + (size_t)k0 * NC + col;
#pragma unroll
    for (int i = 0; i < 8; ++i) b[i] = (f16)wp[i * NC];
    return b;
}

__device__ __forceinline__ void build_ln_a(const float* __restrict__ X, int n0, int lane,
    const float* __restrict__ lng, const float* __restrict__ lnb, f16x8* a)
{
    const int r = lane & 15, c = lane >> 4;
    const float* xp = X + (size_t)(n0 + r) * 64 + c * 8;
    float4 x0 = *(const float4*)(xp);
    float4 x1 = *(const float4*)(xp + 4);
    float4 x2 = *(const float4*)(xp + 32);
    float4 x3 = *(const float4*)(xp + 36);
    float xs[16] = {x0.x, x0.y, x0.z, x0.w, x1.x, x1.y, x1.z, x1.w,
                    x2.x, x2.y, x2.z, x2.w, x3.x, x3.y, x3.z, x3.w};
    float s = 0.f, s2 = 0.f;
#pragma unroll
    for (int i = 0; i < 16; ++i) { s += xs[i]; s2 = fmaf(xs[i], xs[i], s2); }
    s += __shfl_xor(s, 16);  s += __shfl_xor(s, 32);
    s2 += __shfl_xor(s2, 16); s2 += __shfl_xor(s2, 32);
    float mu = s * 0.015625f;
    float var = s2 * 0.015625f - mu * mu;
    float rstd = rsqrtf(fmaxf(var, 0.f) + 1e-5f);
    const float* gp = lng + c * 8;
    const float* bp = lnb + c * 8;
    float4 g0 = *(const float4*)(gp),      g1 = *(const float4*)(gp + 4);
    float4 g2 = *(const float4*)(gp + 32), g3 = *(const float4*)(gp + 36);
    float4 b0 = *(const float4*)(bp),      b1 = *(const float4*)(bp + 4);
    float4 b2 = *(const float4*)(bp + 32), b3 = *(const float4*)(bp + 36);
    float gs[16] = {g0.x, g0.y, g0.z, g0.w, g1.x, g1.y, g1.z, g1.w,
                    g2.x, g2.y, g2.z, g2.w, g3.x, g3.y, g3.z, g3.w};
    float bs[16] = {b0.x, b0.y, b0.z, b0.w, b1.x, b1.y, b1.z, b1.w,
                    b2.x, b2.y, b2.z, b2.w, b3.x, b3.y, b3.z, b3.w};
#pragma unroll
    for (int i = 0; i < 16; ++i) {
        float h = (xs[i] - mu) * rstd * gs[i] + bs[i];
        a[i >> 3][i & 7] = (f16)h;
    }
}

// ---------------- fused LN1 + Q,Skip + K,V projections (two weight phases) ----------------
// QXh row: [q(64 f16)|xr(64 f16)]
__global__ __launch_bounds__(256) void k_proj(const float* __restrict__ X,
    u16* __restrict__ QXh, u32* __restrict__ KV,
    const float* __restrict__ Wq, const float* __restrict__ Ws,
    const float* __restrict__ Wk, const float* __restrict__ Wv,
    const float* __restrict__ bq, const float* __restrict__ bs_,
    const float* __restrict__ bk, const float* __restrict__ bv,
    const float* __restrict__ lng, const float* __restrict__ lnb)
{
    const int lane = threadIdx.x & 63;
    const int wid = (blockIdx.x * 256 + threadIdx.x) >> 6;
    const int nw = gridDim.x * 4;
    const int ch_base = lane & 15;
    const int k0b = (lane >> 4) * 8;
    float bq_l[4], bs_l[4], bk_l[4], bv_l[4];
#pragma unroll
    for (int t = 0; t < 4; ++t) {
        bq_l[t] = bq[t * 16 + ch_base]; bs_l[t] = bs_[t * 16 + ch_base];
        bk_l[t] = bk[t * 16 + ch_base]; bv_l[t] = bv[t * 16 + ch_base];
    }
    for (int g = wid; g < NG; g += nw) {
        int n0 = g * 16;
        f16x8 a[2];
        build_ln_a(X, n0, lane, lng, lnb, a);
        int rbase = n0 + (lane >> 4) * 4;
        // phase 1: Q | Skip -> QXh (f16)
        {
            f16x8 bw[8][2];
#pragma unroll
            for (int t = 0; t < 4; ++t)
#pragma unroll
                for (int s = 0; s < 2; ++s) {
                    bw[t][s]     = load_bfrag(Wq, 64, t * 16 + ch_base, s * 32 + k0b);
                    bw[t + 4][s] = load_bfrag(Ws, 64, t * 16 + ch_base, s * 32 + k0b);
                }
            f32x4 acc[8];
#pragma unroll
            for (int t = 0; t < 8; ++t) { acc[t][0] = 0.f; acc[t][1] = 0.f; acc[t][2] = 0.f; acc[t][3] = 0.f; }
#pragma unroll
            for (int t = 0; t < 8; ++t)
#pragma unroll
                for (int s = 0; s < 2; ++s)
                    acc[t] = __builtin_amdgcn_mfma_f32_16x16x32_f16(a[s], bw[t][s], acc[t], 0, 0, 0);
#pragma unroll
            for (int t = 0; t < 4; ++t) {
                int ch = t * 16 + ch_base;
#pragma unroll
                for (int j = 0; j < 4; ++j) {
                    u16* dst = QXh + (size_t)(rbase + j) * 128;
                    dst[ch] = f2h(acc[t][j] + bq_l[t]);
                    dst[64 + ch] = f2h(acc[t + 4][j] + bs_l[t]);
                }
            }
        }
        // phase 2: K | V -> packed f16 KV
        {
            f16x8 bw[8][2];
#pragma unroll
            for (int t = 0; t < 4; ++t)
#pragma unroll
                for (int s = 0; s < 2; ++s) {
                    bw[t][s]     = load_bfrag(Wk, 64, t * 16 + ch_base, s * 32 + k0b);
                    bw[t + 4][s] = load_bfrag(Wv, 64, t * 16 + ch_base, s * 32 + k0b);
                }
            f32x4 acc[8];
#pragma unroll
            for (int t = 0; t < 8; ++t) { acc[t][0] = 0.f; acc[t][1] = 0.f; acc[t][2] = 0.f; acc[t][3] = 0.f; }
#pragma unroll
            for (int t = 0; t < 8; ++t)
#pragma unroll
                for (int s = 0; s < 2; ++s)
                    acc[t] = __builtin_amdgcn_mfma_f32_16x16x32_f16(a[s], bw[t][s], acc[t], 0, 0, 0);
#pragma unroll
            for (int t = 0; t < 4; ++t) {
                int ch = t * 16 + ch_base;
#pragma unroll
                for (int j = 0; j < 4; ++j) {
                    u32 lo = f2h(acc[t][j] + bk_l[t]);
                    u32 hi = f2h(acc[t + 4][j] + bv_l[t]);
                    KV[(size_t)(rbase + j) * 64 + ch] = (hi << 16) | lo;
                }
            }
        }
    }
}

// ---------------- edge attention: 8-deep interleave, scalar EC loads, fdot2, DPP reduce ----------------
__global__ __launch_bounds__(256) void k_edge(
    const u16* __restrict__ QXh, const u32* __restrict__ KV, float* __restrict__ X,
    const int* __restrict__ rowptr, const i32x4* __restrict__ EC,
    const float* __restrict__ We, const float* __restrict__ Wbeta)
{
    const float SCL = 0.25f * 1.4426950408889634f;
    int lane = threadIdx.x & 63;
    // grid is exact: 12500 blocks * 4 waves = 50000 nodes
    int node = __builtin_amdgcn_readfirstlane(blockIdx.x * 4 + (threadIdx.x >> 6));
    f16x2 w01, w23;
    w01[0] = (f16)We[lane];        w01[1] = (f16)We[64 + lane];
    w23[0] = (f16)We[128 + lane];  w23[1] = (f16)We[192 + lane];
    float wbA = Wbeta[lane] + Wbeta[128 + lane];
    float wbB = Wbeta[64 + lane] - Wbeta[128 + lane];
    const u16* qrow = QXh + (size_t)node * 128;
    float q = h2f(qrow[lane]) * SCL;
    float xr = h2f(qrow[64 + lane]);
    int jb = rowptr[node], je = rowptr[node + 1];
    float l[4] = {0.f, 0.f, 0.f, 0.f};
    float a[4] = {0.f, 0.f, 0.f, 0.f};
    int j = jb;
    for (; j + 7 < je; j += 8) {
        i32x4 r[8]; u32 kv[8];
#pragma unroll
        for (int c = 0; c < 8; ++c) r[c] = EC[j + c];
#pragma unroll
        for (int c = 0; c < 8; ++c) kv[c] = KV[(r[c][0] << 6) | lane];
#pragma unroll
        for (int c = 0; c < 8; ++c) {
            float e = __builtin_amdgcn_fdot2(w01, as_h2((u32)r[c][1]),
                        __builtin_amdgcn_fdot2(w23, as_h2((u32)r[c][2]), 0.f, false), false);
            float ke = h2f_lo(kv[c]) + e;
            float ve = h2f_hi(kv[c]) + e;
            float pe = fexp2(red16(q * ke));
            l[c & 3] += pe;
            a[c & 3] = fmaf(pe, ve, a[c & 3]);
        }
    }
    for (; j + 3 < je; j += 4) {
        i32x4 r[4]; u32 kv[4];
#pragma unroll
        for (int c = 0; c < 4; ++c) r[c] = EC[j + c];
#pragma unroll
        for (int c = 0; c < 4; ++c) kv[c] = KV[(r[c][0] << 6) | lane];
#pragma unroll
        for (int c = 0; c < 4; ++c) {
            float e = __builtin_amdgcn_fdot2(w01, as_h2((u32)r[c][1]),
                        __builtin_amdgcn_fdot2(w23, as_h2((u32)r[c][2]), 0.f, false), false);
            float ke = h2f_lo(kv[c]) + e;
            float ve = h2f_hi(kv[c]) + e;
            float pe = fexp2(red16(q * ke));
            l[c] += pe;
            a[c] = fmaf(pe, ve, a[c]);
        }
    }
    for (; j < je; ++j) {
        i32x4 r0 = EC[j];
        u32 kv0 = KV[(r0[0] << 6) | lane];
        float e0 = __builtin_amdgcn_fdot2(w01, as_h2((u32)r0[1]),
                     __builtin_amdgcn_fdot2(w23, as_h2((u32)r0[2]), 0.f, false), false);
        float ke0 = h2f_lo(kv0) + e0, ve0 = h2f_hi(kv0) + e0;
        float pe0 = fexp2(red16(q * ke0));
        l[0] += pe0;
        a[0] = fmaf(pe0, ve0, a[0]);
    }
    float lsum = (l[0] + l[1]) + (l[2] + l[3]);
    float acc = (a[0] + a[1]) + (a[2] + a[3]);
    float outv = acc / (lsum + 1e-16f);
    float tb = outv * wbA + xr * wbB;
#pragma unroll
    for (int off = 32; off; off >>= 1) tb += __shfl_xor(tb, off);
    float beta = 1.f / (1.f + __expf(-tb));
    float res = beta * xr + (1.f - beta) * outv;
    X[(size_t)node * 64 + lane] += res;
}

// ---------------- LN2 + FFN1 (64->128) + GELU -> G f16 ----------------
__global__ __launch_bounds__(256) void k_ffn1_m(const float* __restrict__ X, u16* __restrict__ G16,
    const float* __restrict__ W1, const float* __restrict__ b1,
    const float* __restrict__ lng, const float* __restrict__ lnb)
{
    const int lane = threadIdx.x & 63;
    const int wid = (blockIdx.x * 256 + threadIdx.x) >> 6;
    const int nw = gridDim.x * 4;
    const int ch_base = lane & 15;
    const int k0b = (lane >> 4) * 8;
    f16x8 bw[8][2];
#pragma unroll
    for (int t = 0; t < 8; ++t)
#pragma unroll
        for (int s = 0; s < 2; ++s)
            bw[t][s] = load_bfrag(W1, 128, t * 16 + ch_base, s * 32 + k0b);
    float b1_l[8];
#pragma unroll
    for (int t = 0; t < 8; ++t) b1_l[t] = b1[t * 16 + ch_base];
    for (int g = wid; g < NG; g += nw) {
        int n0 = g * 16;
        f16x8 a[2];
        build_ln_a(X, n0, lane, lng, lnb, a);
        f32x4 acc[8];
#pragma unroll
        for (int t = 0; t < 8; ++t) { acc[t][0] = 0.f; acc[t][1] = 0.f; acc[t][2] = 0.f; acc[t][3] = 0.f; }
#pragma unroll
        for (int t = 0; t < 8; ++t)
#pragma unroll
            for (int s = 0; s < 2; ++s)
                acc[t] = __builtin_amdgcn_mfma_f32_16x16x32_f16(a[s], bw[t][s], acc[t], 0, 0, 0);
        int rbase = n0 + (lane >> 4) * 4;
#pragma unroll
        for (int t = 0; t < 8; ++t) {
            int ch = t * 16 + ch_base;
#pragma unroll
            for (int j = 0; j < 4; ++j) {
                float v = acc[t][j] + b1_l[t];
                float o = 0.5f * v * (1.f + erff(v * 0.7071067811865476f));
                G16[(size_t)(rbase + j) * 128 + ch] = f2h(o);
            }
        }
    }
}

// ---------------- FFN2 (128->64) + residual into X (+ fused pool on last layer) ----------------
__global__ __launch_bounds__(256) void k_ffn2_m(const u16* __restrict__ G16, float* __restrict__ X,
    const float* __restrict__ W2, const float* __restrict__ b2,
    const int* __restrict__ batch, u32* __restrict__ pkeys, int dopool)
{
    const int lane = threadIdx.x & 63;
    const int wid = (blockIdx.x * 256 + threadIdx.x) >> 6;
    const int nw = gridDim.x * 4;
    const int ch_base = lane & 15;
    const int k0b = (lane >> 4) * 8;
    f16x8 bw[4][4];
#pragma unroll
    for (int t = 0; t < 4; ++t)
#pragma unroll
        for (int s = 0; s < 4; ++s)
            bw[t][s] = load_bfrag(W2, 64, t * 16 + ch_base, s * 32 + k0b);
    float b2_l[4];
#pragma unroll
    for (int t = 0; t < 4; ++t) b2_l[t] = b2[t * 16 + ch_base];
    for (int g = wid; g < NG; g += nw) {
        int n0 = g * 16;
        const u16* gp = G16 + (size_t)(n0 + ch_base) * 128 + k0b;
        f16x8 a0 = *(const f16x8*)(gp);
        f16x8 a1 = *(const f16x8*)(gp + 32);
        f16x8 a2 = *(const f16x8*)(gp + 64);
        f16x8 a3 = *(const f16x8*)(gp + 96);
        f32x4 acc[4];
#pragma unroll
        for (int t = 0; t < 4; ++t) { acc[t][0] = 0.f; acc[t][1] = 0.f; acc[t][2] = 0.f; acc[t][3] = 0.f; }
#pragma unroll
        for (int t = 0; t < 4; ++t) {
            acc[t] = __builtin_amdgcn_mfma_f32_16x16x32_f16(a0, bw[t][0], acc[t], 0, 0, 0);
            acc[t] = __builtin_amdgcn_mfma_f32_16x16x32_f16(a1, bw[t][1], acc[t], 0, 0, 0);
            acc[t] = __builtin_amdgcn_mfma_f32_16x16x32_f16(a2, bw[t][2], acc[t], 0, 0, 0);
            acc[t] = __builtin_amdgcn_mfma_f32_16x16x32_f16(a3, bw[t][3], acc[t], 0, 0, 0);
        }
        int rbase = n0 + (lane >> 4) * 4;
#pragma unroll
        for (int t = 0; t < 4; ++t) {
            int ch = t * 16 + ch_base;
#pragma unroll
            for (int j = 0; j < 4; ++j) {
                int n = rbase + j;
                float* dst = X + (size_t)n * 64 + ch;
                float v = *dst + acc[t][j] + b2_l[t];
                *dst = v;
                if (dopool) {
                    u32 u = __float_as_uint(v);
                    u32 key = (u >> 31) ? ~u : (u | 0x80000000u);
                    atomicMax(&pkeys[batch[n] * 64 + ch], key);
                }
            }
        }
    }
}

// ---------------- head ----------------
__global__ __launch_bounds__(128) void k_head(const u32* __restrict__ pkeys,
    const float* __restrict__ Wo1, const float* __restrict__ bo1,
    const float* __restrict__ Wo2, const float* __restrict__ bo2,
    float* __restrict__ out)
{
    __shared__ float P[64];
    __shared__ float E1[128];
    __shared__ float wred[2];
    int b = blockIdx.x, t = threadIdx.x;
    if (t < 64) {
        u32 k = pkeys[b * 64 + t];
        float v = 0.f;
        if (k) v = (k >> 31) ? __uint_as_float(k ^ 0x80000000u) : __uint_as_float(~k);
        P[t] = v;
    }
    __syncthreads();
    float a = bo1[t];
#pragma unroll 8
    for (int k = 0; k < 64; ++k) a = fmaf(P[k], Wo1[k * 128 + t], a);
    E1[t] = fmaxf(a, 0.f);
    __syncthreads();
    float o = bo2[t];
#pragma unroll 8
    for (int k = 0; k < 128; ++k) o = fmaf(E1[k], Wo2[k * 128 + t], o);
    float ss = o * o;
#pragma unroll
    for (int off = 32; off; off >>= 1) ss += __shfl_xor(ss, off);
    if ((t & 63) == 0) wred[t >> 6] = ss;
    __syncthreads();
    float tot = wred[0] + wred[1];
    float nrm = fmaxf(sqrtf(tot), 1e-12f);
    out[b * 128 + t] = o / nrm;
}

// ---------------- launch ----------------
extern "C" void kernel_launch(void* const* d_in, const int* in_sizes, int n_in,
                              void* d_out, int out_size, void* d_ws, size_t ws_size,
                              hipStream_t stream)
{
    const float* x         = (const float*)d_in[0];
    const float* edge_attr = (const float*)d_in[1];
    const int* ei          = (const int*)d_in[2];
    const int* batch       = (const int*)d_in[3];
    const float* Win  = (const float*)d_in[4];
    const float* bin  = (const float*)d_in[5];
    const float* ln1g = (const float*)d_in[6];
    const float* ln1b = (const float*)d_in[7];
    const float* Wq   = (const float*)d_in[8];
    const float* bq   = (const float*)d_in[9];
    const float* Wk   = (const float*)d_in[10];
    const float* bk   = (const float*)d_in[11];
    const float* Wv   = (const float*)d_in[12];
    const float* bv   = (const float*)d_in[13];
    const float* We   = (const float*)d_in[14];
    const float* Wsk  = (const float*)d_in[15];
    const float* bsk  = (const float*)d_in[16];
    const float* Wbe  = (const float*)d_in[17];
    const float* ln2g = (const float*)d_in[18];
    const float* ln2b = (const float*)d_in[19];
    const float* W1   = (const float*)d_in[20];
    const float* b1   = (const float*)d_in[21];
    const float* W2   = (const float*)d_in[22];
    const float* b2   = (const float*)d_in[23];
    const float* Wo1  = (const float*)d_in[24];
    const float* bo1  = (const float*)d_in[25];
    const float* Wo2  = (const float*)d_in[26];
    const float* bo2  = (const float*)d_in[27];

    char* wsp = (char*)d_ws;
    size_t off = 0;
    auto alloc = [&](size_t bytes) { void* p = wsp + off; off = (off + bytes + 255) & ~(size_t)255; return p; };
    float*   X      = (float*)alloc((size_t)Nn * 64 * 4);
    u16*     QXh    = (u16*)alloc((size_t)Nn * 128 * 2);
    u32*     KV     = (u32*)alloc((size_t)Nn * 64 * 4);
    u16*     G16    = (u16*)alloc((size_t)Nn * 128 * 2);
    int*     rowptr = (int*)alloc((size_t)(Nn + 1) * 4);
    int*     deg    = (int*)alloc((size_t)Nn * 4);
    int*     cursor = (int*)alloc((size_t)Nn * 4);
    int*     psum   = (int*)alloc((size_t)SCB * 4);
    int*     poff   = (int*)alloc((size_t)SCB * 4);
    i32x4*   EC     = (i32x4*)alloc((size_t)Ee * 16);
    u32*     pkeys  = (u32*)alloc((size_t)Bb * 64 * 4);

    hipMemsetAsync(deg, 0, (size_t)Nn * 4, stream);
    hipMemsetAsync(cursor, 0, (size_t)Nn * 4, stream);
    hipMemsetAsync(pkeys, 0, (size_t)Bb * 64 * 4, stream);

    k_input_proj<<<12500, 256, 0, stream>>>(x, Win, bin, X);
    k_hist<<<(Ee + 255) / 256, 256, 0, stream>>>(ei, deg);
    k_part<<<SCB, 256, 0, stream>>>(deg, psum);
    k_scanp<<<1, 256, 0, stream>>>(psum, poff);
    k_apply<<<SCB, 256, 0, stream>>>(deg, poff, rowptr);
    k_scatter<<<(Ee + 255) / 256, 256, 0, stream>>>(ei, edge_attr, rowptr, cursor, EC);

    for (int l = 0; l < 3; ++l) {
        k_proj<<<GB, 256, 0, stream>>>(X, QXh, KV,
            Wq + l * 4096, Wsk + l * 4096, Wk + l * 4096, Wv + l * 4096,
            bq + l * 64, bsk + l * 64, bk + l * 64, bv + l * 64,
            ln1g + l * 64, ln1b + l * 64);
        k_edge<<<Nn / 4, 256, 0, stream>>>(QXh, KV, X, rowptr, EC,
            We + l * 256, Wbe + l * 192);
        k_ffn1_m<<<GB, 256, 0, stream>>>(X, G16, W1 + l * 8192, b1 + l * 128,
            ln2g + l * 64, ln2b + l * 64);
        k_ffn2_m<<<GB, 256, 0, stream>>>(G16, X, W2 + l * 8192, b2 + l * 64,
            batch, pkeys, (l == 2) ? 1 : 0);
    }
    k_head<<<Bb, 128, 0, stream>>>(pkeys, Wo1, bo1, Wo2, bo2, (float*)d_out);
}

// Round 13
// 435.743 us; speedup vs baseline: 1.1599x; 1.0044x over previous
//
#include <hip/hip_runtime.h>
#include <hip/hip_bf16.h>
#include <hip/hip_fp16.h>

#define Nn 50000
#define Ee 1000000
#define Bb 512
#define NG 3125   // 50000/16 node-row groups (exact)
#define SCB 196   // ceil(50000/256) scan blocks
#define GB 782    // dense-kernel grid: 782*4=3128 waves >= 3125 groups (1 group/wave)

typedef unsigned short u16;
typedef unsigned int u32;
typedef _Float16 f16;
typedef _Float16 f16x2 __attribute__((ext_vector_type(2)));
typedef _Float16 f16x8 __attribute__((ext_vector_type(8)));
typedef float f32x4 __attribute__((ext_vector_type(4)));
typedef int i32x4 __attribute__((ext_vector_type(4)));

__device__ __forceinline__ u16 f2h(float f) { return __half_as_ushort(__float2half(f)); }
__device__ __forceinline__ float h2f(u16 h) { return __half2float(__ushort_as_half(h)); }
__device__ __forceinline__ float h2f_lo(u32 kv) { return __half2float(__ushort_as_half((u16)(kv & 0xffff))); }
__device__ __forceinline__ float h2f_hi(u32 kv) { return __half2float(__ushort_as_half((u16)(kv >> 16))); }
__device__ __forceinline__ f16x2 as_h2(u32 v) { union { u32 u; f16x2 h; } c; c.u = v; return c.h; }

__device__ __forceinline__ float fexp2(float x) {
    float r;
    asm("v_exp_f32 %0, %1" : "=v"(r) : "v"(x));
    return r;
}

// butterfly sum over each 16-lane group (one head) via DPP
__device__ __forceinline__ float red16(float x) {
    int t;
    t = __builtin_amdgcn_update_dpp(0, __float_as_int(x), 0xB1, 0xF, 0xF, true);   // quad_perm [1,0,3,2]
    x += __int_as_float(t);
    t = __builtin_amdgcn_update_dpp(0, __float_as_int(x), 0x4E, 0xF, 0xF, true);   // quad_perm [2,3,0,1]
    x += __int_as_float(t);
    t = __builtin_amdgcn_update_dpp(0, __float_as_int(x), 0x141, 0xF, 0xF, true);  // row_half_mirror
    x += __int_as_float(t);
    t = __builtin_amdgcn_update_dpp(0, __float_as_int(x), 0x140, 0xF, 0xF, true);  // row_mirror
    x += __int_as_float(t);
    return x;
}

// ---------------- input projection ----------------
__global__ __launch_bounds__(256) void k_input_proj(const float* __restrict__ x,
    const float* __restrict__ Win, const float* __restrict__ bin, float* __restrict__ X)
{
    __shared__ float W[8][64];
    __shared__ float bsh[64];
    int t = threadIdx.x;
    if (t < 64) bsh[t] = bin[t];
    for (int i = t; i < 512; i += 256) W[i >> 6][i & 63] = Win[i];
    __syncthreads();
    int gid = blockIdx.x * 256 + t;
    int n = gid >> 6, c = gid & 63;
    const float* xr = x + n * 8;
    float acc = bsh[c];
#pragma unroll
    for (int k = 0; k < 8; ++k) acc = fmaf(xr[k], W[k][c], acc);
    X[gid] = acc;
}

// ---------------- CSR build ----------------
__global__ __launch_bounds__(256) void k_hist(const int* __restrict__ ei, int* __restrict__ deg)
{
    int e = blockIdx.x * 256 + threadIdx.x;
    if (e < Ee) atomicAdd(&deg[ei[Ee + e]], 1);
}

__global__ __launch_bounds__(256) void k_part(const int* __restrict__ deg, int* __restrict__ psum)
{
    __shared__ int ws[4];
    int b = blockIdx.x, t = threadIdx.x;
    int idx = b * 256 + t;
    int v = (idx < Nn) ? deg[idx] : 0;
    int r = v;
#pragma unroll
    for (int off = 32; off; off >>= 1) r += __shfl_xor(r, off);
    if ((t & 63) == 0) ws[t >> 6] = r;
    __syncthreads();
    if (t == 0) psum[b] = ws[0] + ws[1] + ws[2] + ws[3];
}

__global__ __launch_bounds__(256) void k_scanp(const int* __restrict__ psum, int* __restrict__ poff)
{
    __shared__ int ws[4];
    int t = threadIdx.x, lane = t & 63, w = t >> 6;
    int v = (t < SCB) ? psum[t] : 0;
    int s = v;
#pragma unroll
    for (int off = 1; off < 64; off <<= 1) {
        int u = __shfl_up(s, off);
        if (lane >= off) s += u;
    }
    if (lane == 63) ws[w] = s;
    __syncthreads();
    if (t == 0) { int a = 0; for (int i = 0; i < 4; ++i) { a += ws[i]; ws[i] = a; } }
    __syncthreads();
    int incl = s + (w ? ws[w - 1] : 0);
    if (t < SCB) poff[t] = incl - v;
}

__global__ __launch_bounds__(256) void k_apply(const int* __restrict__ deg, const int* __restrict__ poff,
    int* __restrict__ rowptr)
{
    __shared__ int ws[4];
    int b = blockIdx.x, t = threadIdx.x, lane = t & 63, w = t >> 6;
    int idx = b * 256 + t;
    int v = (idx < Nn) ? deg[idx] : 0;
    int s = v;
#pragma unroll
    for (int off = 1; off < 64; off <<= 1) {
        int u = __shfl_up(s, off);
        if (lane >= off) s += u;
    }
    if (lane == 63) ws[w] = s;
    __syncthreads();
    if (t == 0) { int a = 0; for (int i = 0; i < 4; ++i) { a += ws[i]; ws[i] = a; } }
    __syncthreads();
    int incl = s + (w ? ws[w - 1] : 0) + poff[b];
    if (idx < Nn) rowptr[idx + 1] = incl;
    if (b == 0 && t == 0) rowptr[0] = 0;
}

// scatter one packed 16B record per edge: {src, (a1|a0) f16, (a3|a2) f16, 0}
__global__ __launch_bounds__(256) void k_scatter(const int* __restrict__ ei, const float* __restrict__ eattr,
    const int* __restrict__ rowptr, int* __restrict__ cursor, i32x4* __restrict__ EC)
{
    int e = blockIdx.x * 256 + threadIdx.x;
    if (e >= Ee) return;
    int d = ei[Ee + e];
    int pos = rowptr[d] + atomicAdd(&cursor[d], 1);
    float4 ea = *(const float4*)(eattr + (size_t)e * 4);
    i32x4 rec;
    rec[0] = ei[e];
    rec[1] = (int)(((u32)f2h(ea.y) << 16) | f2h(ea.x));
    rec[2] = (int)(((u32)f2h(ea.w) << 16) | f2h(ea.z));
    rec[3] = 0;
    EC[pos] = rec;
}

// ---------------- MFMA helpers ----------------
__device__ __forceinline__ f16x8 load_bfrag(const float* __restrict__ W, int NC, int col, int k0)
{
    f16x8 b;
    const float* wp = W + (size_t)k0 * NC + col;
#pragma unroll
    for (int i = 0; i < 8; ++i) b[i] = (f16)wp[i * NC];
    return b;
}

__device__ __forceinline__ void build_ln_a(const float* __restrict__ X, int n0, int lane,
    const float* __restrict__ lng, const float* __restrict__ lnb, f16x8* a)
{
    const int r = lane & 15, c = lane >> 4;
    const float* xp = X + (size_t)(n0 + r) * 64 + c * 8;
    float4 x0 = *(const float4*)(xp);
    float4 x1 = *(const float4*)(xp + 4);
    float4 x2 = *(const float4*)(xp + 32);
    float4 x3 = *(const float4*)(xp + 36);
    float xs[16] = {x0.x, x0.y, x0.z, x0.w, x1.x, x1.y, x1.z, x1.w,
                    x2.x, x2.y, x2.z, x2.w, x3.x, x3.y, x3.z, x3.w};
    float s = 0.f, s2 = 0.f;
#pragma unroll
    for (int i = 0; i < 16; ++i) { s += xs[i]; s2 = fmaf(xs[i], xs[i], s2); }
    s += __shfl_xor(s, 16);  s += __shfl_xor(s, 32);
    s2 += __shfl_xor(s2, 16); s2 += __shfl_xor(s2, 32);
    float mu = s * 0.015625f;
    float var = s2 * 0.015625f - mu * mu;
    float rstd = rsqrtf(fmaxf(var, 0.f) + 1e-5f);
    const float* gp = lng + c * 8;
    const float* bp = lnb + c * 8;
    float4 g0 = *(const float4*)(gp),      g1 = *(const float4*)(gp + 4);
    float4 g2 = *(const float4*)(gp + 32), g3 = *(const float4*)(gp + 36);
    float4 b0 = *(const float4*)(bp),      b1 = *(const float4*)(bp + 4);
    float4 b2 = *(const float4*)(bp + 32), b3 = *(const float4*)(bp + 36);
    float gs[16] = {g0.x, g0.y, g0.z, g0.w, g1.x, g1.y, g1.z, g1.w,
                    g2.x, g2.y, g2.z, g2.w, g3.x, g3.y, g3.z, g3.w};
    float bs[16] = {b0.x, b0.y, b0.z, b0.w, b1.x, b1.y, b1.z, b1.w,
                    b2.x, b2.y, b2.z, b2.w, b3.x, b3.y, b3.z, b3.w};
#pragma unroll
    for (int i = 0; i < 16; ++i) {
        float h = (xs[i] - mu) * rstd * gs[i] + bs[i];
        a[i >> 3][i & 7] = (f16)h;
    }
}

// ---------------- fused LN1 + Q,Skip + K,V projections (two weight phases) ----------------
// QXh row: [q(64 f16)|xr(64 f16)]
__global__ __launch_bounds__(256) void k_proj(const float* __restrict__ X,
    u16* __restrict__ QXh, u32* __restrict__ KV,
    const float* __restrict__ Wq, const float* __restrict__ Ws,
    const float* __restrict__ Wk, const float* __restrict__ Wv,
    const float* __restrict__ bq, const float* __restrict__ bs_,
    const float* __restrict__ bk, const float* __restrict__ bv,
    const float* __restrict__ lng, const float* __restrict__ lnb)
{
    const int lane = threadIdx.x & 63;
    const int wid = (blockIdx.x * 256 + threadIdx.x) >> 6;
    const int nw = gridDim.x * 4;
    const int ch_base = lane & 15;
    const int k0b = (lane >> 4) * 8;
    float bq_l[4], bs_l[4], bk_l[4], bv_l[4];
#pragma unroll
    for (int t = 0; t < 4; ++t) {
        bq_l[t] = bq[t * 16 + ch_base]; bs_l[t] = bs_[t * 16 + ch_base];
        bk_l[t] = bk[t * 16 + ch_base]; bv_l[t] = bv[t * 16 + ch_base];
    }
    for (int g = wid; g < NG; g += nw) {
        int n0 = g * 16;
        f16x8 a[2];
        build_ln_a(X, n0, lane, lng, lnb, a);
        int rbase = n0 + (lane >> 4) * 4;
        // phase 1: Q | Skip -> QXh (f16)
        {
            f16x8 bw[8][2];
#pragma unroll
            for (int t = 0; t < 4; ++t)
#pragma unroll
                for (int s = 0; s < 2; ++s) {
                    bw[t][s]     = load_bfrag(Wq, 64, t * 16 + ch_base, s * 32 + k0b);
                    bw[t + 4][s] = load_bfrag(Ws, 64, t * 16 + ch_base, s * 32 + k0b);
                }
            f32x4 acc[8];
#pragma unroll
            for (int t = 0; t < 8; ++t) { acc[t][0] = 0.f; acc[t][1] = 0.f; acc[t][2] = 0.f; acc[t][3] = 0.f; }
#pragma unroll
            for (int t = 0; t < 8; ++t)
#pragma unroll
                for (int s = 0; s < 2; ++s)
                    acc[t] = __builtin_amdgcn_mfma_f32_16x16x32_f16(a[s], bw[t][s], acc[t], 0, 0, 0);
#pragma unroll
            for (int t = 0; t < 4; ++t) {
                int ch = t * 16 + ch_base;
#pragma unroll
                for (int j = 0; j < 4; ++j) {
                    u16* dst = QXh + (size_t)(rbase + j) * 128;
                    dst[ch] = f2h(acc[t][j] + bq_l[t]);
                    dst[64 + ch] = f2h(acc[t + 4][j] + bs_l[t]);
                }
            }
        }
        // phase 2: K | V -> packed f16 KV
        {
            f16x8 bw[8][2];
#pragma unroll
            for (int t = 0; t < 4; ++t)
#pragma unroll
                for (int s = 0; s < 2; ++s) {
                    bw[t][s]     = load_bfrag(Wk, 64, t * 16 + ch_base, s * 32 + k0b);
                    bw[t + 4][s] = load_bfrag(Wv, 64, t * 16 + ch_base, s * 32 + k0b);
                }
            f32x4 acc[8];
#pragma unroll
            for (int t = 0; t < 8; ++t) { acc[t][0] = 0.f; acc[t][1] = 0.f; acc[t][2] = 0.f; acc[t][3] = 0.f; }
#pragma unroll
            for (int t = 0; t < 8; ++t)
#pragma unroll
                for (int s = 0; s < 2; ++s)
                    acc[t] = __builtin_amdgcn_mfma_f32_16x16x32_f16(a[s], bw[t][s], acc[t], 0, 0, 0);
#pragma unroll
            for (int t = 0; t < 4; ++t) {
                int ch = t * 16 + ch_base;
#pragma unroll
                for (int j = 0; j < 4; ++j) {
                    u32 lo = f2h(acc[t][j] + bk_l[t]);
                    u32 hi = f2h(acc[t + 4][j] + bv_l[t]);
                    KV[(size_t)(rbase + j) * 64 + ch] = (hi << 16) | lo;
                }
            }
        }
    }
}

// ---------------- edge attention: 8-deep interleave, scalar EC loads, fdot2, DPP reduce ----------------
__global__ __launch_bounds__(256) void k_edge(
    const u16* __restrict__ QXh, const u32* __restrict__ KV, float* __restrict__ X,
    const int* __restrict__ rowptr, const i32x4* __restrict__ EC,
    const float* __restrict__ We, const float* __restrict__ Wbeta)
{
    const float SCL = 0.25f * 1.4426950408889634f;
    int lane = threadIdx.x & 63;
    // grid is exact: 12500 blocks * 4 waves = 50000 nodes
    int node = __builtin_amdgcn_readfirstlane(blockIdx.x * 4 + (threadIdx.x >> 6));
    f16x2 w01, w23;
    w01[0] = (f16)We[lane];        w01[1] = (f16)We[64 + lane];
    w23[0] = (f16)We[128 + lane];  w23[1] = (f16)We[192 + lane];
    float wbA = Wbeta[lane] + Wbeta[128 + lane];
    float wbB = Wbeta[64 + lane] - Wbeta[128 + lane];
    const u16* qrow = QXh + (size_t)node * 128;
    float q = h2f(qrow[lane]) * SCL;
    float xr = h2f(qrow[64 + lane]);
    int jb = rowptr[node], je = rowptr[node + 1];
    float l[4] = {0.f, 0.f, 0.f, 0.f};
    float a[4] = {0.f, 0.f, 0.f, 0.f};
    int j = jb;
    for (; j + 7 < je; j += 8) {
        i32x4 r[8]; u32 kv[8];
#pragma unroll
        for (int c = 0; c < 8; ++c) r[c] = EC[j + c];
#pragma unroll
        for (int c = 0; c < 8; ++c) kv[c] = KV[(r[c][0] << 6) | lane];
#pragma unroll
        for (int c = 0; c < 8; ++c) {
            float e = __builtin_amdgcn_fdot2(w01, as_h2((u32)r[c][1]),
                        __builtin_amdgcn_fdot2(w23, as_h2((u32)r[c][2]), 0.f, false), false);
            float ke = h2f_lo(kv[c]) + e;
            float ve = h2f_hi(kv[c]) + e;
            float pe = fexp2(red16(q * ke));
            l[c & 3] += pe;
            a[c & 3] = fmaf(pe, ve, a[c & 3]);
        }
    }
    for (; j < je; ++j) {
        i32x4 r0 = EC[j];
        u32 kv0 = KV[(r0[0] << 6) | lane];
        float e0 = __builtin_amdgcn_fdot2(w01, as_h2((u32)r0[1]),
                     __builtin_amdgcn_fdot2(w23, as_h2((u32)r0[2]), 0.f, false), false);
        float ke0 = h2f_lo(kv0) + e0, ve0 = h2f_hi(kv0) + e0;
        float pe0 = fexp2(red16(q * ke0));
        l[0] += pe0;
        a[0] = fmaf(pe0, ve0, a[0]);
    }
    float lsum = (l[0] + l[1]) + (l[2] + l[3]);
    float acc = (a[0] + a[1]) + (a[2] + a[3]);
    float outv = acc / (lsum + 1e-16f);
    float tb = outv * wbA + xr * wbB;
#pragma unroll
    for (int off = 32; off; off >>= 1) tb += __shfl_xor(tb, off);
    float beta = 1.f / (1.f + __expf(-tb));
    float res = beta * xr + (1.f - beta) * outv;
    X[(size_t)node * 64 + lane] += res;
}

// ---------------- LN2 + FFN1 (64->128) + GELU -> G f16 ----------------
__global__ __launch_bounds__(256) void k_ffn1_m(const float* __restrict__ X, u16* __restrict__ G16,
    const float* __restrict__ W1, const float* __restrict__ b1,
    const float* __restrict__ lng, const float* __restrict__ lnb)
{
    const int lane = threadIdx.x & 63;
    const int wid = (blockIdx.x * 256 + threadIdx.x) >> 6;
    const int nw = gridDim.x * 4;
    const int ch_base = lane & 15;
    const int k0b = (lane >> 4) * 8;
    f16x8 bw[8][2];
#pragma unroll
    for (int t = 0; t < 8; ++t)
#pragma unroll
        for (int s = 0; s < 2; ++s)
            bw[t][s] = load_bfrag(W1, 128, t * 16 + ch_base, s * 32 + k0b);
    float b1_l[8];
#pragma unroll
    for (int t = 0; t < 8; ++t) b1_l[t] = b1[t * 16 + ch_base];
    for (int g = wid; g < NG; g += nw) {
        int n0 = g * 16;
        f16x8 a[2];
        build_ln_a(X, n0, lane, lng, lnb, a);
        f32x4 acc[8];
#pragma unroll
        for (int t = 0; t < 8; ++t) { acc[t][0] = 0.f; acc[t][1] = 0.f; acc[t][2] = 0.f; acc[t][3] = 0.f; }
#pragma unroll
        for (int t = 0; t < 8; ++t)
#pragma unroll
            for (int s = 0; s < 2; ++s)
                acc[t] = __builtin_amdgcn_mfma_f32_16x16x32_f16(a[s], bw[t][s], acc[t], 0, 0, 0);
        int rbase = n0 + (lane >> 4) * 4;
#pragma unroll
        for (int t = 0; t < 8; ++t) {
            int ch = t * 16 + ch_base;
#pragma unroll
            for (int j = 0; j < 4; ++j) {
                float v = acc[t][j] + b1_l[t];
                float o = 0.5f * v * (1.f + erff(v * 0.7071067811865476f));
                G16[(size_t)(rbase + j) * 128 + ch] = f2h(o);
            }
        }
    }
}

// ---------------- FFN2 (128->64) + residual into X (+ fused pool on last layer) ----------------
__global__ __launch_bounds__(256) void k_ffn2_m(const u16* __restrict__ G16, float* __restrict__ X,
    const float* __restrict__ W2, const float* __restrict__ b2,
    const int* __restrict__ batch, u32* __restrict__ pkeys, int dopool)
{
    const int lane = threadIdx.x & 63;
    const int wid = (blockIdx.x * 256 + threadIdx.x) >> 6;
    const int nw = gridDim.x * 4;
    const int ch_base = lane & 15;
    const int k0b = (lane >> 4) * 8;
    f16x8 bw[4][4];
#pragma unroll
    for (int t = 0; t < 4; ++t)
#pragma unroll
        for (int s = 0; s < 4; ++s)
            bw[t][s] = load_bfrag(W2, 64, t * 16 + ch_base, s * 32 + k0b);
    float b2_l[4];
#pragma unroll
    for (int t = 0; t < 4; ++t) b2_l[t] = b2[t * 16 + ch_base];
    for (int g = wid; g < NG; g += nw) {
        int n0 = g * 16;
        const u16* gp = G16 + (size_t)(n0 + ch_base) * 128 + k0b;
        f16x8 a0 = *(const f16x8*)(gp);
        f16x8 a1 = *(const f16x8*)(gp + 32);
        f16x8 a2 = *(const f16x8*)(gp + 64);
        f16x8 a3 = *(const f16x8*)(gp + 96);
        f32x4 acc[4];
#pragma unroll
        for (int t = 0; t < 4; ++t) { acc[t][0] = 0.f; acc[t][1] = 0.f; acc[t][2] = 0.f; acc[t][3] = 0.f; }
#pragma unroll
        for (int t = 0; t < 4; ++t) {
            acc[t] = __builtin_amdgcn_mfma_f32_16x16x32_f16(a0, bw[t][0], acc[t], 0, 0, 0);
            acc[t] = __builtin_amdgcn_mfma_f32_16x16x32_f16(a1, bw[t][1], acc[t], 0, 0, 0);
            acc[t] = __builtin_amdgcn_mfma_f32_16x16x32_f16(a2, bw[t][2], acc[t], 0, 0, 0);
            acc[t] = __builtin_amdgcn_mfma_f32_16x16x32_f16(a3, bw[t][3], acc[t], 0, 0, 0);
        }
        int rbase = n0 + (lane >> 4) * 4;
#pragma unroll
        for (int t = 0; t < 4; ++t) {
            int ch = t * 16 + ch_base;
#pragma unroll
            for (int j = 0; j < 4; ++j) {
                int n = rbase + j;
                float* dst = X + (size_t)n * 64 + ch;
                float v = *dst + acc[t][j] + b2_l[t];
                *dst = v;
                if (dopool) {
                    u32 u = __float_as_uint(v);
                    u32 key = (u >> 31) ? ~u : (u | 0x80000000u);
                    atomicMax(&pkeys[batch[n] * 64 + ch], key);
                }
            }
        }
    }
}

// ---------------- head ----------------
__global__ __launch_bounds__(128) void k_head(const u32* __restrict__ pkeys,
    const float* __restrict__ Wo1, const float* __restrict__ bo1,
    const float* __restrict__ Wo2, const float* __restrict__ bo2,
    float* __restrict__ out)
{
    __shared__ float P[64];
    __shared__ float E1[128];
    __shared__ float wred[2];
    int b = blockIdx.x, t = threadIdx.x;
    if (t < 64) {
        u32 k = pkeys[b * 64 + t];
        float v = 0.f;
        if (k) v = (k >> 31) ? __uint_as_float(k ^ 0x80000000u) : __uint_as_float(~k);
        P[t] = v;
    }
    __syncthreads();
    float a = bo1[t];
#pragma unroll 8
    for (int k = 0; k < 64; ++k) a = fmaf(P[k], Wo1[k * 128 + t], a);
    E1[t] = fmaxf(a, 0.f);
    __syncthreads();
    float o = bo2[t];
#pragma unroll 8
    for (int k = 0; k < 128; ++k) o = fmaf(E1[k], Wo2[k * 128 + t], o);
    float ss = o * o;
#pragma unroll
    for (int off = 32; off; off >>= 1) ss += __shfl_xor(ss, off);
    if ((t & 63) == 0) wred[t >> 6] = ss;
    __syncthreads();
    float tot = wred[0] + wred[1];
    float nrm = fmaxf(sqrtf(tot), 1e-12f);
    out[b * 128 + t] = o / nrm;
}

// ---------------- launch ----------------
extern "C" void kernel_launch(void* const* d_in, const int* in_sizes, int n_in,
                              void* d_out, int out_size, void* d_ws, size_t ws_size,
                              hipStream_t stream)
{
    const float* x         = (const float*)d_in[0];
    const float* edge_attr = (const float*)d_in[1];
    const int* ei          = (const int*)d_in[2];
    const int* batch       = (const int*)d_in[3];
    const float* Win  = (const float*)d_in[4];
    const float* bin  = (const float*)d_in[5];
    const float* ln1g = (const float*)d_in[6];
    const float* ln1b = (const float*)d_in[7];
    const float* Wq   = (const float*)d_in[8];
    const float* bq   = (const float*)d_in[9];
    const float* Wk   = (const float*)d_in[10];
    const float* bk   = (const float*)d_in[11];
    const float* Wv   = (const float*)d_in[12];
    const float* bv   = (const float*)d_in[13];
    const float* We   = (const float*)d_in[14];
    const float* Wsk  = (const float*)d_in[15];
    const float* bsk  = (const float*)d_in[16];
    const float* Wbe  = (const float*)d_in[17];
    const float* ln2g = (const float*)d_in[18];
    const float* ln2b = (const float*)d_in[19];
    const float* W1   = (const float*)d_in[20];
    const float* b1   = (const float*)d_in[21];
    const float* W2   = (const float*)d_in[22];
    const float* b2   = (const float*)d_in[23];
    const float* Wo1  = (const float*)d_in[24];
    const float* bo1  = (const float*)d_in[25];
    const float* Wo2  = (const float*)d_in[26];
    const float* bo2  = (const float*)d_in[27];

    char* wsp = (char*)d_ws;
    size_t off = 0;
    auto alloc = [&](size_t bytes) { void* p = wsp + off; off = (off + bytes + 255) & ~(size_t)255; return p; };
    float*   X      = (float*)alloc((size_t)Nn * 64 * 4);
    u16*     QXh    = (u16*)alloc((size_t)Nn * 128 * 2);
    u32*     KV     = (u32*)alloc((size_t)Nn * 64 * 4);
    u16*     G16    = (u16*)alloc((size_t)Nn * 128 * 2);
    int*     rowptr = (int*)alloc((size_t)(Nn + 1) * 4);
    int*     deg    = (int*)alloc((size_t)Nn * 4);
    int*     cursor = (int*)alloc((size_t)Nn * 4);
    int*     psum   = (int*)alloc((size_t)SCB * 4);
    int*     poff   = (int*)alloc((size_t)SCB * 4);
    i32x4*   EC     = (i32x4*)alloc((size_t)Ee * 16);
    u32*     pkeys  = (u32*)alloc((size_t)Bb * 64 * 4);

    hipMemsetAsync(deg, 0, (size_t)Nn * 4, stream);
    hipMemsetAsync(cursor, 0, (size_t)Nn * 4, stream);
    hipMemsetAsync(pkeys, 0, (size_t)Bb * 64 * 4, stream);

    k_input_proj<<<12500, 256, 0, stream>>>(x, Win, bin, X);
    k_hist<<<(Ee + 255) / 256, 256, 0, stream>>>(ei, deg);
    k_part<<<SCB, 256, 0, stream>>>(deg, psum);
    k_scanp<<<1, 256, 0, stream>>>(psum, poff);
    k_apply<<<SCB, 256, 0, stream>>>(deg, poff, rowptr);
    k_scatter<<<(Ee + 255) / 256, 256, 0, stream>>>(ei, edge_attr, rowptr, cursor, EC);

    for (int l = 0; l < 3; ++l) {
        k_proj<<<GB, 256, 0, stream>>>(X, QXh, KV,
            Wq + l * 4096, Wsk + l * 4096, Wk + l * 4096, Wv + l * 4096,
            bq + l * 64, bsk + l * 64, bk + l * 64, bv + l * 64,
            ln1g + l * 64, ln1b + l * 64);
        k_edge<<<Nn / 4, 256, 0, stream>>>(QXh, KV, X, rowptr, EC,
            We + l * 256, Wbe + l * 192);
        k_ffn1_m<<<GB, 256, 0, stream>>>(X, G16, W1 + l * 8192, b1 + l * 128,
            ln2g + l * 64, ln2b + l * 64);
        k_ffn2_m<<<GB, 256, 0, stream>>>(G16, X, W2 + l * 8192, b2 + l * 64,
            batch, pkeys, (l == 2) ? 1 : 0);
    }
    k_head<<<Bb, 128, 0, stream>>>(pkeys, Wo1, bo1, Wo2, bo2, (float*)d_out);
}